// Round 3
// baseline (603.474 us; speedup 1.0000x reference)
//
#include <hip/hip_runtime.h>
#include <math.h>
#include <stdint.h>

#define B_ 2
#define S_ 2048
#define D_ 1024
#define H_ 8
#define NT_ (B_*S_)   // 4096 tokens

static constexpr float LAMBDA_INIT = 0.47071301834358415f;
static constexpr float ONE_MINUS_LI = 1.0f - 0.47071301834358415f;

typedef __attribute__((ext_vector_type(8))) short bf16x8;
typedef __attribute__((ext_vector_type(4))) float f32x4;

__device__ __forceinline__ unsigned short f2bf(float x) {
    union { float f; unsigned int u; } v; v.f = x;
    unsigned int r = v.u + 0x7fffu + ((v.u >> 16) & 1u);
    return (unsigned short)(r >> 16);
}
__device__ __forceinline__ float bf2f(unsigned short b) {
    union { unsigned int u; float f; } v; v.u = ((unsigned int)b) << 16;
    return v.f;
}

#define GLD16(gp, lp) __builtin_amdgcn_global_load_lds( \
    (const __attribute__((address_space(1))) void*)(gp), \
    (__attribute__((address_space(3))) void*)(lp), 16, 0, 0)

// ---------------------------------------------------------------- lam scalar
__global__ void lam_kernel(const float* __restrict__ lq1, const float* __restrict__ lk1,
                           const float* __restrict__ lq2, const float* __restrict__ lk2,
                           float* __restrict__ lam_out) {
    int t = threadIdx.x;  // 64 threads
    float p1 = lq1[t] * lk1[t];
    float p2 = lq2[t] * lk2[t];
    for (int off = 32; off; off >>= 1) {
        p1 += __shfl_xor(p1, off);
        p2 += __shfl_xor(p2, off);
    }
    if (t == 0) lam_out[0] = expf(p1) - expf(p2) + LAMBDA_INIT;
}

// ---------------------------------------------------------------- f32 -> bf16
__global__ __launch_bounds__(256) void convert_bf16(const float* __restrict__ in,
                                                    short* __restrict__ out) {
    const size_t i = ((size_t)blockIdx.x * 256 + threadIdx.x) * 4;
    float4 v = *(const float4*)(in + i);
    ushort4 o = make_ushort4(f2bf(v.x), f2bf(v.y), f2bf(v.z), f2bf(v.w));
    *(ushort4*)(out + i) = o;
}

// --------------------------------------------- transpose + convert W[K][N] -> WT[N][K]
__global__ __launch_bounds__(256) void transpose_to_bf16(const float* __restrict__ W,
                                                         short* __restrict__ WT,
                                                         int K, int N) {
    __shared__ float tile[32][33];
    const int t = threadIdx.x;
    const int k0 = blockIdx.y * 32, n0 = blockIdx.x * 32;
    const int r = t >> 3, c0 = (t & 7) * 4;
    float4 v = *(const float4*)(W + (size_t)(k0 + r) * N + n0 + c0);
    tile[r][c0 + 0] = v.x; tile[r][c0 + 1] = v.y;
    tile[r][c0 + 2] = v.z; tile[r][c0 + 3] = v.w;
    __syncthreads();
    ushort4 o = make_ushort4(f2bf(tile[c0 + 0][r]), f2bf(tile[c0 + 1][r]),
                             f2bf(tile[c0 + 2][r]), f2bf(tile[c0 + 3][r]));
    *(ushort4*)(WT + (size_t)(n0 + r) * K + k0 + c0) = o;
}

// --------------------------------------------- V transpose: qkv V part -> vt[bh][e][s]
__global__ __launch_bounds__(256) void vtrans_kernel(const short* __restrict__ qkv_bf,
                                                     short* __restrict__ vt) {
    __shared__ short tile[32][34];
    const int s0 = blockIdx.x * 32, e0 = blockIdx.y * 32, bh = blockIdx.z;
    const int b = bh >> 3, h = bh & 7;
    const int t = threadIdx.x, r = t >> 3, c0 = (t & 7) * 4;
    ushort4 v = *(const ushort4*)(qkv_bf + (size_t)(b * S_ + s0 + r) * 3072 + 2048 + h * 128 + e0 + c0);
    tile[r][c0 + 0] = v.x; tile[r][c0 + 1] = v.y;
    tile[r][c0 + 2] = v.z; tile[r][c0 + 3] = v.w;
    __syncthreads();
    ushort4 o = make_ushort4((unsigned short)tile[c0 + 0][r], (unsigned short)tile[c0 + 1][r],
                             (unsigned short)tile[c0 + 2][r], (unsigned short)tile[c0 + 3][r]);
    *(ushort4*)(vt + ((size_t)bh * 128 + e0 + r) * S_ + s0 + c0) = o;
}

// ---------------------------------------------------------------- bf16 MFMA GEMM
// C[M,N] = A[M,K] @ BT[N,K]^T.  128x128 tile, BK=32, 4 waves, 4x4 16x16 frags/wave.
template <int EPI, int OUTBF>
__global__ __launch_bounds__(256) void gemm_bt(const short* __restrict__ A,
                                               const short* __restrict__ BT,
                                               const float* __restrict__ bias,
                                               void* __restrict__ Cout,
                                               int M, int N, int K) {
    __shared__ short As[128 * 32];   // [row][k] 64B rows
    __shared__ short Bs[128 * 32];
    const int t = threadIdx.x;
    const int w = t >> 6, l = t & 63;
    const int lr = l & 15, lg = l >> 4;
    const int row0 = blockIdx.y * 128, col0 = blockIdx.x * 128;
    const int wr = (w >> 1) * 64, wc = (w & 1) * 64;

    f32x4 acc[4][4];
#pragma unroll
    for (int i = 0; i < 4; ++i)
#pragma unroll
        for (int j = 0; j < 4; ++j) acc[i][j] = (f32x4){0.f, 0.f, 0.f, 0.f};

    const short* Ag = A + (size_t)(row0 + w * 32 + (l >> 2)) * K + (l & 3) * 8;
    const short* Bg = BT + (size_t)(col0 + w * 32 + (l >> 2)) * K + (l & 3) * 8;

    for (int k0 = 0; k0 < K; k0 += 32) {
        __syncthreads();
#pragma unroll
        for (int j = 0; j < 2; ++j) {
            GLD16(Ag + k0 + (size_t)j * 16 * K, As + (w * 2 + j) * 512);
            GLD16(Bg + k0 + (size_t)j * 16 * K, Bs + (w * 2 + j) * 512);
        }
        __syncthreads();

        bf16x8 af[4], bfr[4];
#pragma unroll
        for (int i = 0; i < 4; ++i)
            af[i] = *(const bf16x8*)(As + (wr + i * 16 + lr) * 32 + lg * 8);
#pragma unroll
        for (int j = 0; j < 4; ++j)
            bfr[j] = *(const bf16x8*)(Bs + (wc + j * 16 + lr) * 32 + lg * 8);
#pragma unroll
        for (int i = 0; i < 4; ++i)
#pragma unroll
            for (int j = 0; j < 4; ++j)
                acc[i][j] = __builtin_amdgcn_mfma_f32_16x16x32_bf16(af[i], bfr[j], acc[i][j], 0, 0, 0);
    }

#pragma unroll
    for (int i = 0; i < 4; ++i) {
#pragma unroll
        for (int j = 0; j < 4; ++j) {
            const int col = col0 + wc + j * 16 + lr;
            float bcol = (EPI >= 1) ? bias[col] : 0.f;
#pragma unroll
            for (int r = 0; r < 4; ++r) {
                const int row = row0 + wr + i * 16 + lg * 4 + r;
                float v = acc[i][j][r];
                if (EPI >= 1) v += bcol;
                if (EPI == 2) v = v / (1.0f + expf(-v));
                if (OUTBF) ((short*)Cout)[(size_t)row * N + col] = (short)f2bf(v);
                else       ((float*)Cout)[(size_t)row * N + col] = v;
            }
        }
    }
}

// ------------------------------------------------- RoPE + split + q2/k2 RMSNorm (bf16 io)
__global__ __launch_bounds__(256) void rope_kernel(const short* __restrict__ qkv,
                                                   const float* __restrict__ sigmas,
                                                   const float* __restrict__ lnq_w,
                                                   const float* __restrict__ lnq_b,
                                                   short* __restrict__ q1, short* __restrict__ q2n,
                                                   short* __restrict__ k1, short* __restrict__ k2n) {
    const int tok = blockIdx.x;            // 0..4095
    const int b = tok >> 11, s = tok & 2047;
    const int t = threadIdx.x;
    const int hh = t >> 4;                 // 0..15 (head in 2H layout)
    const int d0 = (t & 15) * 4;

    const short* qrow = qkv + (size_t)tok * 3072 + hh * 64 + d0;
    ushort4 qv = *(const ushort4*)qrow;
    ushort4 kv = *(const ushort4*)(qrow + 1024);
    float q[4] = {bf2f(qv.x), bf2f(qv.y), bf2f(qv.z), bf2f(qv.w)};
    float k[4] = {bf2f(kv.x), bf2f(kv.y), bf2f(kv.z), bf2f(kv.w)};

    if (d0 < 32) {
#pragma unroll
        for (int pr = 0; pr < 2; ++pr) {
            const int i = d0 / 2 + pr;
            float freq = (float)s * powf(10000.0f, -(float)i / 16.0f);
            float sn, c;
            sincosf(freq, &sn, &c);
            float x0 = q[2 * pr], x1 = q[2 * pr + 1];
            q[2 * pr]     = x0 * c - x1 * sn;
            q[2 * pr + 1] = x1 * c + x0 * sn;
            x0 = k[2 * pr]; x1 = k[2 * pr + 1];
            k[2 * pr]     = x0 * c - x1 * sn;
            k[2 * pr + 1] = x1 * c + x0 * sn;
        }
    }

    const int h = hh >> 1, j = hh & 1;
    const size_t obase = ((size_t)(b * H_ + h) * S_ + s) * 64 + d0;
    if (j == 0) {
        *(ushort4*)&q1[obase] = make_ushort4(f2bf(q[0]), f2bf(q[1]), f2bf(q[2]), f2bf(q[3]));
        *(ushort4*)&k1[obase] = make_ushort4(f2bf(k[0]), f2bf(k[1]), f2bf(k[2]), f2bf(k[3]));
    } else {
        float ssq_q = 0.f, ssq_k = 0.f;
#pragma unroll
        for (int i = 0; i < 4; ++i) {
            const float sg = sigmas[b * 64 + d0 + i];
            q[i] += sg; k[i] += sg;
            ssq_q += q[i] * q[i];
            ssq_k += k[i] * k[i];
        }
        for (int off = 1; off < 16; off <<= 1) {
            ssq_q += __shfl_xor(ssq_q, off, 16);
            ssq_k += __shfl_xor(ssq_k, off, 16);
        }
        const float rq = rsqrtf(ssq_q / 64.0f + 1e-8f);
        const float rk = rsqrtf(ssq_k / 64.0f + 1e-8f);
        float oq[4], ok[4];
#pragma unroll
        for (int i = 0; i < 4; ++i) {
            const float w = lnq_w[d0 + i], bb = lnq_b[d0 + i];
            oq[i] = q[i] * rq * w + bb;
            ok[i] = k[i] * rk * w + bb;
        }
        *(ushort4*)&q2n[obase] = make_ushort4(f2bf(oq[0]), f2bf(oq[1]), f2bf(oq[2]), f2bf(oq[3]));
        *(ushort4*)&k2n[obase] = make_ushort4(f2bf(ok[0]), f2bf(ok[1]), f2bf(ok[2]), f2bf(ok[3]));
    }
}

// ------------------------------------------------- softmax update (per wave, one branch)
__device__ __forceinline__ void sm_update(f32x4 (&s)[4], float (&m)[4], float (&lsum)[4],
                                          f32x4 (&o)[8], short* __restrict__ Pw,
                                          const bool diag, const int qr0, const int k0,
                                          const int lr, const int lg) {
    float nm[4];
#pragma unroll
    for (int r = 0; r < 4; ++r) nm[r] = m[r];
#pragma unroll
    for (int ks = 0; ks < 4; ++ks) {
#pragma unroll
        for (int r = 0; r < 4; ++r) {
            float v = s[ks][r];
            if (diag && (k0 + ks * 16 + lr > qr0 + r)) v = -INFINITY;
            else v *= 0.125f;
            s[ks][r] = v;
            nm[r] = fmaxf(nm[r], v);
        }
    }
#pragma unroll
    for (int r = 0; r < 4; ++r) {
        nm[r] = fmaxf(nm[r], __shfl_xor(nm[r], 1));
        nm[r] = fmaxf(nm[r], __shfl_xor(nm[r], 2));
        nm[r] = fmaxf(nm[r], __shfl_xor(nm[r], 4));
        nm[r] = fmaxf(nm[r], __shfl_xor(nm[r], 8));
    }
    float al[4], rs[4];
#pragma unroll
    for (int r = 0; r < 4; ++r) { al[r] = __expf(m[r] - nm[r]); m[r] = nm[r]; rs[r] = 0.f; }
#pragma unroll
    for (int ks = 0; ks < 4; ++ks) {
#pragma unroll
        for (int r = 0; r < 4; ++r) {
            float p = __expf(s[ks][r] - nm[r]);
            rs[r] += p;
            Pw[(lg * 4 + r) * 72 + ks * 16 + lr] = (short)f2bf(p);
        }
    }
#pragma unroll
    for (int r = 0; r < 4; ++r) {
        rs[r] += __shfl_xor(rs[r], 1);
        rs[r] += __shfl_xor(rs[r], 2);
        rs[r] += __shfl_xor(rs[r], 4);
        rs[r] += __shfl_xor(rs[r], 8);
        lsum[r] = lsum[r] * al[r] + rs[r];
    }
#pragma unroll
    for (int es = 0; es < 8; ++es) {
#pragma unroll
        for (int r = 0; r < 4; ++r) o[es][r] *= al[r];
    }
}

// ------------------------------------------------- dual attention, split-K partials
// grid: (64 = qt*2+part, H, B).  Block = 4 waves, wave w = 16 Q rows. No barriers.
__global__ __launch_bounds__(256, 3) void attn_part(const short* __restrict__ q1g,
                                                    const short* __restrict__ q2g,
                                                    const short* __restrict__ k1g,
                                                    const short* __restrict__ k2g,
                                                    const short* __restrict__ vt,
                                                    short* __restrict__ pO0,
                                                    short* __restrict__ pO1,
                                                    float* __restrict__ pml) {
    __shared__ short Ps[4][2][16 * 72];   // [wave][branch][row][72]

    const int bx = blockIdx.x;
    const int qt = bx >> 1, part = bx & 1;
    const int h = blockIdx.y, b = blockIdx.z, bh = b * H_ + h;
    const int q0 = qt * 64;
    const int t = threadIdx.x, w = t >> 6, l = t & 63;
    const int lr = l & 15, lg = l >> 4;

    const size_t kbase = (size_t)bh * S_ * 64;
    const size_t vbase = (size_t)bh * 128 * S_;

    // Q fragments
    bf16x8 qa1[2], qa2[2];
    {
        const size_t rb = kbase + (size_t)(q0 + w * 16 + lr) * 64;
#pragma unroll
        for (int dh = 0; dh < 2; ++dh) {
            qa1[dh] = *(const bf16x8*)(q1g + rb + dh * 32 + lg * 8);
            qa2[dh] = *(const bf16x8*)(q2g + rb + dh * 32 + lg * 8);
        }
    }

    const int nkt = qt + 1, mid = (nkt + 1) >> 1;
    const int kt0 = part ? mid : 0, kt1 = part ? nkt : mid;

    float m1[4], m2[4], l1[4], l2[4];
#pragma unroll
    for (int r = 0; r < 4; ++r) { m1[r] = -INFINITY; m2[r] = -INFINITY; l1[r] = 0.f; l2[r] = 0.f; }
    f32x4 o1[8], o2[8];
#pragma unroll
    for (int es = 0; es < 8; ++es) { o1[es] = (f32x4){0.f,0.f,0.f,0.f}; o2[es] = (f32x4){0.f,0.f,0.f,0.f}; }

    short* Pw1 = &Ps[w][0][0];
    short* Pw2 = &Ps[w][1][0];
    const int qr0 = q0 + w * 16 + lg * 4;

    for (int kt = kt0; kt < kt1; ++kt) {
        const int k0 = kt * 64;
        const bool diag = (kt == qt);

        // QK^T branch 1
        f32x4 s1[4];
#pragma unroll
        for (int ks = 0; ks < 4; ++ks) s1[ks] = (f32x4){0.f,0.f,0.f,0.f};
#pragma unroll
        for (int ks = 0; ks < 4; ++ks) {
#pragma unroll
            for (int dh = 0; dh < 2; ++dh) {
                bf16x8 kf = *(const bf16x8*)(k1g + kbase + (size_t)(k0 + ks * 16 + lr) * 64 + dh * 32 + lg * 8);
                s1[ks] = __builtin_amdgcn_mfma_f32_16x16x32_bf16(qa1[dh], kf, s1[ks], 0, 0, 0);
            }
        }
        sm_update(s1, m1, l1, o1, Pw1, diag, qr0, k0, lr, lg);

        // QK^T branch 2
        f32x4 s2[4];
#pragma unroll
        for (int ks = 0; ks < 4; ++ks) s2[ks] = (f32x4){0.f,0.f,0.f,0.f};
#pragma unroll
        for (int ks = 0; ks < 4; ++ks) {
#pragma unroll
            for (int dh = 0; dh < 2; ++dh) {
                bf16x8 kf = *(const bf16x8*)(k2g + kbase + (size_t)(k0 + ks * 16 + lr) * 64 + dh * 32 + lg * 8);
                s2[ks] = __builtin_amdgcn_mfma_f32_16x16x32_bf16(qa2[dh], kf, s2[ks], 0, 0, 0);
            }
        }
        sm_update(s2, m2, l2, o2, Pw2, diag, qr0, k0, lr, lg);

        // PV both branches (V fragments direct from global V^T)
#pragma unroll
        for (int kb = 0; kb < 2; ++kb) {
            bf16x8 p1f = *(const bf16x8*)((const char*)Pw1 + lr * 144 + kb * 64 + lg * 16);
            bf16x8 p2f = *(const bf16x8*)((const char*)Pw2 + lr * 144 + kb * 64 + lg * 16);
#pragma unroll
            for (int es = 0; es < 8; ++es) {
                bf16x8 vf = *(const bf16x8*)(vt + vbase + (size_t)(es * 16 + lr) * S_ + k0 + kb * 32 + lg * 8);
                o1[es] = __builtin_amdgcn_mfma_f32_16x16x32_bf16(p1f, vf, o1[es], 0, 0, 0);
                o2[es] = __builtin_amdgcn_mfma_f32_16x16x32_bf16(p2f, vf, o2[es], 0, 0, 0);
            }
        }
    }

    // store partials (O unnormalized, bf16; m,l f32)
    short* pO = part ? pO1 : pO0;
#pragma unroll
    for (int r = 0; r < 4; ++r) {
        const int q = q0 + w * 16 + lg * 4 + r;
        const size_t ob = ((size_t)bh * S_ + q) * 256;
#pragma unroll
        for (int es = 0; es < 8; ++es) {
            pO[ob + es * 16 + lr]       = (short)f2bf(o1[es][r]);
            pO[ob + 128 + es * 16 + lr] = (short)f2bf(o2[es][r]);
        }
    }
    if (lr == 0) {
#pragma unroll
        for (int r = 0; r < 4; ++r) {
            const int q = q0 + w * 16 + lg * 4 + r;
            float4 v = make_float4(m1[r], l1[r], m2[r], l2[r]);
            *(float4*)&pml[(((size_t)part * 16 + bh) * S_ + q) * 4] = v;
        }
    }
}

// ------------------------------------------------- combine partials + diff + RMSNorm
__global__ __launch_bounds__(256) void attn_combine(const short* __restrict__ pO0,
                                                    const short* __restrict__ pO1,
                                                    const float* __restrict__ pml,
                                                    const float* __restrict__ lamp,
                                                    const float* __restrict__ ln_w,
                                                    const float* __restrict__ ln_b,
                                                    short* __restrict__ arms) {
    const int tok = blockIdx.x;           // 0..4095
    const int b = tok >> 11, q = tok & 2047;
    const int t = threadIdx.x;
    const int h = t >> 5, ln32 = t & 31, e0 = ln32 * 4;
    const int bh = b * H_ + h;
    const float lam = lamp[0];

    float4 mla = *(const float4*)&pml[(((size_t)0 * 16 + bh) * S_ + q) * 4];
    float4 mlb = *(const float4*)&pml[(((size_t)1 * 16 + bh) * S_ + q) * 4];

    const float m1 = fmaxf(mla.x, mlb.x);
    const float aa1 = __expf(mla.x - m1), ab1 = __expf(mlb.x - m1);
    const float il1 = 1.0f / (aa1 * mla.y + ab1 * mlb.y);
    const float m2 = fmaxf(mla.z, mlb.z);
    const float aa2 = __expf(mla.z - m2), ab2 = __expf(mlb.z - m2);
    const float il2 = 1.0f / (aa2 * mla.w + ab2 * mlb.w);

    const size_t ob = ((size_t)bh * S_ + q) * 256;
    ushort4 oa1 = *(const ushort4*)&pO0[ob + e0];
    ushort4 ob1 = *(const ushort4*)&pO1[ob + e0];
    ushort4 oa2 = *(const ushort4*)&pO0[ob + 128 + e0];
    ushort4 ob2 = *(const ushort4*)&pO1[ob + 128 + e0];

    float comb[4]; float ssq = 0.f;
    {
        const unsigned short* a1 = (const unsigned short*)&oa1;
        const unsigned short* b1v = (const unsigned short*)&ob1;
        const unsigned short* a2 = (const unsigned short*)&oa2;
        const unsigned short* b2v = (const unsigned short*)&ob2;
#pragma unroll
        for (int i = 0; i < 4; ++i) {
            const float O1 = (aa1 * bf2f(a1[i]) + ab1 * bf2f(b1v[i])) * il1;
            const float O2 = (aa2 * bf2f(a2[i]) + ab2 * bf2f(b2v[i])) * il2;
            const float c = O1 - lam * O2;
            comb[i] = c; ssq += c * c;
        }
    }
    for (int off = 1; off < 32; off <<= 1) ssq += __shfl_xor(ssq, off, 32);
    const float rms = rsqrtf(ssq / 128.0f + 1e-8f);

    ushort4 o;
    unsigned short* op = (unsigned short*)&o;
#pragma unroll
    for (int i = 0; i < 4; ++i) {
        const int e = e0 + i;
        op[i] = f2bf((comb[i] * rms * ln_w[e] + ln_b[e]) * ONE_MINUS_LI);
    }
    *(ushort4*)&arms[(size_t)tok * 1024 + h * 128 + e0] = o;
}

// ---------------------------------------------------------------- add + LayerNorm
template <int WB>
__global__ __launch_bounds__(256) void add_ln_kernel(const float* __restrict__ X,
                                                     const float* __restrict__ Y,
                                                     const float* __restrict__ w,
                                                     const float* __restrict__ bvec,
                                                     float* __restrict__ out,
                                                     short* __restrict__ out_bf,
                                                     float eps) {
    const int row = blockIdx.x;
    const int t = threadIdx.x;
    __shared__ float red[4];

    float4 xv = *(const float4*)&X[(size_t)row * 1024 + t * 4];
    float4 yv = *(const float4*)&Y[(size_t)row * 1024 + t * 4];
    float v[4] = {xv.x + yv.x, xv.y + yv.y, xv.z + yv.z, xv.w + yv.w};

    float s = v[0] + v[1] + v[2] + v[3];
    for (int off = 1; off < 64; off <<= 1) s += __shfl_xor(s, off);
    if ((t & 63) == 0) red[t >> 6] = s;
    __syncthreads();
    const float mean = (red[0] + red[1] + red[2] + red[3]) * (1.0f / 1024.0f);

    float sq = 0.f;
#pragma unroll
    for (int i = 0; i < 4; ++i) { const float d = v[i] - mean; sq += d * d; }
    __syncthreads();
    for (int off = 1; off < 64; off <<= 1) sq += __shfl_xor(sq, off);
    if ((t & 63) == 0) red[t >> 6] = sq;
    __syncthreads();
    const float var = (red[0] + red[1] + red[2] + red[3]) * (1.0f / 1024.0f);
    const float rstd = rsqrtf(var + eps);

    float o[4];
#pragma unroll
    for (int i = 0; i < 4; ++i)
        o[i] = (v[i] - mean) * rstd * w[t * 4 + i] + bvec[t * 4 + i];
    *(float4*)&out[(size_t)row * 1024 + t * 4] = make_float4(o[0], o[1], o[2], o[3]);
    if (WB) {
        *(ushort4*)&out_bf[(size_t)row * 1024 + t * 4] =
            make_ushort4(f2bf(o[0]), f2bf(o[1]), f2bf(o[2]), f2bf(o[3]));
    }
}

// ---------------------------------------------------------------- launch
extern "C" void kernel_launch(void* const* d_in, const int* in_sizes, int n_in,
                              void* d_out, int out_size, void* d_ws, size_t ws_size,
                              hipStream_t stream) {
    const float* x      = (const float*)d_in[0];
    const float* sigmas = (const float*)d_in[1];
    const float* w_qkv  = (const float*)d_in[2];
    const float* w_out  = (const float*)d_in[3];
    const float* lq1    = (const float*)d_in[4];
    const float* lk1    = (const float*)d_in[5];
    const float* lq2    = (const float*)d_in[6];
    const float* lk2    = (const float*)d_in[7];
    const float* ln_w   = (const float*)d_in[8];
    const float* ln_b   = (const float*)d_in[9];
    const float* lnq_w  = (const float*)d_in[10];
    const float* lnq_b  = (const float*)d_in[11];
    const float* ln1_w  = (const float*)d_in[12];
    const float* ln1_b  = (const float*)d_in[13];
    const float* ln2_w  = (const float*)d_in[14];
    const float* ln2_b  = (const float*)d_in[15];
    const float* w1     = (const float*)d_in[16];
    const float* b1     = (const float*)d_in[17];
    const float* w2     = (const float*)d_in[18];
    const float* b2     = (const float*)d_in[19];

    char* ws = (char*)d_ws;
    short* x_bf    = (short*)(ws + 0);            //  8,388,608 (-> vt after qkv gemm)
    short* vt      = (short*)(ws + 0);            //  8,388,608 exactly
    short* w_qkvT  = (short*)(ws + 8388608);      //  6,291,456
    short* w_outT  = (short*)(ws + 14680064);     //  2,097,152
    short* w1T     = (short*)(ws + 16777216);     //  8,388,608
    short* w2T     = (short*)(ws + 25165824);     //  8,388,608
    short* qkv_bf  = (short*)(ws + 33554432);     // 25,165,824 (dead after rope+vtrans)
    short* pO0     = (short*)(ws + 33554432);     // 16,777,216
    float* pml     = (float*)(ws + 50331648);     //  1,048,576
    short* q1      = (short*)(ws + 58720256);     //  4,194,304
    short* q2n     = (short*)(ws + 62914560);
    short* k1      = (short*)(ws + 67108864);
    short* k2n     = (short*)(ws + 71303168);     // ends 75,497,472
    short* arms    = (short*)(ws + 75497472);     //  8,388,608
    short* pO1     = (short*)(ws + 83886080);     // 16,777,216 (-> a_f32 after combine)
    float* a_f32   = (float*)(ws + 83886080);
    float* h_f32   = (float*)(ws + 33554432);     // reuse pO0+pml region after combine
    short* h_bf    = (short*)(ws + 50331648);     //  8,388,608
    short* ffh     = (short*)(ws + 58720256);     // 33,554,432 (q/k + arms dead)
    float* ff      = (float*)(ws + 0);            // 16,777,216 (vt + w_qkvT dead)
    float* lam     = (float*)(ws + 100663296);

    // 1. lambda
    lam_kernel<<<1, 64, 0, stream>>>(lq1, lk1, lq2, lk2, lam);

    // 2. conversions
    convert_bf16<<<4096, 256, 0, stream>>>(x, x_bf);
    transpose_to_bf16<<<dim3(3072 / 32, 1024 / 32), 256, 0, stream>>>(w_qkv, w_qkvT, 1024, 3072);
    transpose_to_bf16<<<dim3(1024 / 32, 1024 / 32), 256, 0, stream>>>(w_out, w_outT, 1024, 1024);
    transpose_to_bf16<<<dim3(4096 / 32, 1024 / 32), 256, 0, stream>>>(w1, w1T, 1024, 4096);
    transpose_to_bf16<<<dim3(1024 / 32, 4096 / 32), 256, 0, stream>>>(w2, w2T, 4096, 1024);

    // 3. qkv = x @ w_qkv  -> bf16
    gemm_bt<0, 1><<<dim3(3072 / 128, 4096 / 128), 256, 0, stream>>>(x_bf, w_qkvT, nullptr,
                                                                    qkv_bf, NT_, 3072, 1024);

    // 4. rope + split + q2/k2 rmsnorm ; V transpose (x_bf dead now)
    rope_kernel<<<NT_, 256, 0, stream>>>(qkv_bf, sigmas, lnq_w, lnq_b, q1, q2n, k1, k2n);
    vtrans_kernel<<<dim3(S_ / 32, 4, 16), 256, 0, stream>>>(qkv_bf, vt);

    // 5. dual attention split-K partials + combine (qkv_bf dead after vtrans)
    attn_part<<<dim3(64, H_, B_), 256, 0, stream>>>(q1, q2n, k1, k2n, vt, pO0, pO1, pml);
    attn_combine<<<NT_, 256, 0, stream>>>(pO0, pO1, pml, lam, ln_w, ln_b, arms);

    // 6. a = arms @ w_out -> f32
    gemm_bt<0, 0><<<dim3(1024 / 128, 4096 / 128), 256, 0, stream>>>(arms, w_outT, nullptr,
                                                                    a_f32, NT_, 1024, 1024);

    // 7. h = LN(a + x) -> f32 + bf16
    add_ln_kernel<1><<<NT_, 256, 0, stream>>>(a_f32, x, ln1_w, ln1_b, h_f32, h_bf, 1e-5f);

    // 8. ffh = silu(h @ w1 + b1) -> bf16
    gemm_bt<2, 1><<<dim3(4096 / 128, 4096 / 128), 256, 0, stream>>>(h_bf, w1T, b1,
                                                                    ffh, NT_, 4096, 1024);

    // 9. ff = ffh @ w2 + b2 -> f32
    gemm_bt<1, 0><<<dim3(1024 / 128, 4096 / 128), 256, 0, stream>>>(ffh, w2T, b2,
                                                                    ff, NT_, 1024, 4096);

    // 10. out = LN(ff + h)
    add_ln_kernel<0><<<NT_, 256, 0, stream>>>(ff, h_f32, ln2_w, ln2_b, (float*)d_out,
                                              nullptr, 1e-5f);
}

// Round 4
// 442.493 us; speedup vs baseline: 1.3638x; 1.3638x over previous
//
#include <hip/hip_runtime.h>
#include <math.h>
#include <stdint.h>

#define B_ 2
#define S_ 2048
#define D_ 1024
#define H_ 8
#define NT_ (B_*S_)   // 4096 tokens

static constexpr float LAMBDA_INIT = 0.47071301834358415f;
static constexpr float ONE_MINUS_LI = 1.0f - 0.47071301834358415f;

typedef __attribute__((ext_vector_type(8))) short bf16x8;
typedef __attribute__((ext_vector_type(4))) float f32x4;

__device__ __forceinline__ unsigned short f2bf(float x) {
    union { float f; unsigned int u; } v; v.f = x;
    unsigned int r = v.u + 0x7fffu + ((v.u >> 16) & 1u);
    return (unsigned short)(r >> 16);
}
__device__ __forceinline__ float bf2f(unsigned short b) {
    union { unsigned int u; float f; } v; v.u = ((unsigned int)b) << 16;
    return v.f;
}

#define GLD16(gp, lp) __builtin_amdgcn_global_load_lds( \
    (const __attribute__((address_space(1))) void*)(gp), \
    (__attribute__((address_space(3))) void*)(lp), 16, 0, 0)

// ---------------------------------------------------------------- lam scalar
__global__ void lam_kernel(const float* __restrict__ lq1, const float* __restrict__ lk1,
                           const float* __restrict__ lq2, const float* __restrict__ lk2,
                           float* __restrict__ lam_out) {
    int t = threadIdx.x;  // 64 threads
    float p1 = lq1[t] * lk1[t];
    float p2 = lq2[t] * lk2[t];
    for (int off = 32; off; off >>= 1) {
        p1 += __shfl_xor(p1, off);
        p2 += __shfl_xor(p2, off);
    }
    if (t == 0) lam_out[0] = expf(p1) - expf(p2) + LAMBDA_INIT;
}

// ---------------------------------------------------------------- f32 -> bf16
__global__ __launch_bounds__(256) void convert_bf16(const float* __restrict__ in,
                                                    short* __restrict__ out) {
    const size_t i = ((size_t)blockIdx.x * 256 + threadIdx.x) * 4;
    float4 v = *(const float4*)(in + i);
    ushort4 o = make_ushort4(f2bf(v.x), f2bf(v.y), f2bf(v.z), f2bf(v.w));
    *(ushort4*)(out + i) = o;
}

// --------------------------------------------- transpose + convert W[K][N] -> WT[N][K]
__global__ __launch_bounds__(256) void transpose_to_bf16(const float* __restrict__ W,
                                                         short* __restrict__ WT,
                                                         int K, int N) {
    __shared__ float tile[32][33];
    const int t = threadIdx.x;
    const int k0 = blockIdx.y * 32, n0 = blockIdx.x * 32;
    const int r = t >> 3, c0 = (t & 7) * 4;
    float4 v = *(const float4*)(W + (size_t)(k0 + r) * N + n0 + c0);
    tile[r][c0 + 0] = v.x; tile[r][c0 + 1] = v.y;
    tile[r][c0 + 2] = v.z; tile[r][c0 + 3] = v.w;
    __syncthreads();
    ushort4 o = make_ushort4(f2bf(tile[c0 + 0][r]), f2bf(tile[c0 + 1][r]),
                             f2bf(tile[c0 + 2][r]), f2bf(tile[c0 + 3][r]));
    *(ushort4*)(WT + (size_t)(n0 + r) * K + k0 + c0) = o;
}

// --------------------------------------------- V transpose: qkv V part -> vt[bh][e][s]
__global__ __launch_bounds__(256) void vtrans_kernel(const short* __restrict__ qkv_bf,
                                                     short* __restrict__ vt) {
    __shared__ short tile[32][34];
    const int s0 = blockIdx.x * 32, e0 = blockIdx.y * 32, bh = blockIdx.z;
    const int b = bh >> 3, h = bh & 7;
    const int t = threadIdx.x, r = t >> 3, c0 = (t & 7) * 4;
    ushort4 v = *(const ushort4*)(qkv_bf + (size_t)(b * S_ + s0 + r) * 3072 + 2048 + h * 128 + e0 + c0);
    tile[r][c0 + 0] = v.x; tile[r][c0 + 1] = v.y;
    tile[r][c0 + 2] = v.z; tile[r][c0 + 3] = v.w;
    __syncthreads();
    ushort4 o = make_ushort4((unsigned short)tile[c0 + 0][r], (unsigned short)tile[c0 + 1][r],
                             (unsigned short)tile[c0 + 2][r], (unsigned short)tile[c0 + 3][r]);
    *(ushort4*)(vt + ((size_t)bh * 128 + e0 + r) * S_ + s0 + c0) = o;
}

// ---------------------------------------------------------------- bf16 MFMA GEMM
// C[M,N] = A[M,K] @ BT[N,K]^T.  128x128 tile, BK=32, 4 waves, 4x4 16x16 frags/wave.
template <int EPI, int OUTBF>
__global__ __launch_bounds__(256) void gemm_bt(const short* __restrict__ A,
                                               const short* __restrict__ BT,
                                               const float* __restrict__ bias,
                                               void* __restrict__ Cout,
                                               int M, int N, int K) {
    __shared__ short As[128 * 32];   // [row][k] 64B rows
    __shared__ short Bs[128 * 32];
    const int t = threadIdx.x;
    const int w = t >> 6, l = t & 63;
    const int lr = l & 15, lg = l >> 4;
    const int row0 = blockIdx.y * 128, col0 = blockIdx.x * 128;
    const int wr = (w >> 1) * 64, wc = (w & 1) * 64;

    f32x4 acc[4][4];
#pragma unroll
    for (int i = 0; i < 4; ++i)
#pragma unroll
        for (int j = 0; j < 4; ++j) acc[i][j] = (f32x4){0.f, 0.f, 0.f, 0.f};

    const short* Ag = A + (size_t)(row0 + w * 32 + (l >> 2)) * K + (l & 3) * 8;
    const short* Bg = BT + (size_t)(col0 + w * 32 + (l >> 2)) * K + (l & 3) * 8;

    for (int k0 = 0; k0 < K; k0 += 32) {
        __syncthreads();
#pragma unroll
        for (int j = 0; j < 2; ++j) {
            GLD16(Ag + k0 + (size_t)j * 16 * K, As + (w * 2 + j) * 512);
            GLD16(Bg + k0 + (size_t)j * 16 * K, Bs + (w * 2 + j) * 512);
        }
        __syncthreads();

        bf16x8 af[4], bfr[4];
#pragma unroll
        for (int i = 0; i < 4; ++i)
            af[i] = *(const bf16x8*)(As + (wr + i * 16 + lr) * 32 + lg * 8);
#pragma unroll
        for (int j = 0; j < 4; ++j)
            bfr[j] = *(const bf16x8*)(Bs + (wc + j * 16 + lr) * 32 + lg * 8);
#pragma unroll
        for (int i = 0; i < 4; ++i)
#pragma unroll
            for (int j = 0; j < 4; ++j)
                acc[i][j] = __builtin_amdgcn_mfma_f32_16x16x32_bf16(af[i], bfr[j], acc[i][j], 0, 0, 0);
    }

#pragma unroll
    for (int i = 0; i < 4; ++i) {
#pragma unroll
        for (int j = 0; j < 4; ++j) {
            const int col = col0 + wc + j * 16 + lr;
            float bcol = (EPI >= 1) ? bias[col] : 0.f;
#pragma unroll
            for (int r = 0; r < 4; ++r) {
                const int row = row0 + wr + i * 16 + lg * 4 + r;
                float v = acc[i][j][r];
                if (EPI >= 1) v += bcol;
                if (EPI == 2) v = v / (1.0f + expf(-v));
                if (OUTBF) ((short*)Cout)[(size_t)row * N + col] = (short)f2bf(v);
                else       ((float*)Cout)[(size_t)row * N + col] = v;
            }
        }
    }
}

// ------------------------------------------------- RoPE + split + q2/k2 RMSNorm (bf16 io)
__global__ __launch_bounds__(256) void rope_kernel(const short* __restrict__ qkv,
                                                   const float* __restrict__ sigmas,
                                                   const float* __restrict__ lnq_w,
                                                   const float* __restrict__ lnq_b,
                                                   short* __restrict__ q1, short* __restrict__ q2n,
                                                   short* __restrict__ k1, short* __restrict__ k2n) {
    const int tok = blockIdx.x;            // 0..4095
    const int b = tok >> 11, s = tok & 2047;
    const int t = threadIdx.x;
    const int hh = t >> 4;                 // 0..15 (head in 2H layout)
    const int d0 = (t & 15) * 4;

    const short* qrow = qkv + (size_t)tok * 3072 + hh * 64 + d0;
    ushort4 qv = *(const ushort4*)qrow;
    ushort4 kv = *(const ushort4*)(qrow + 1024);
    float q[4] = {bf2f(qv.x), bf2f(qv.y), bf2f(qv.z), bf2f(qv.w)};
    float k[4] = {bf2f(kv.x), bf2f(kv.y), bf2f(kv.z), bf2f(kv.w)};

    if (d0 < 32) {
#pragma unroll
        for (int pr = 0; pr < 2; ++pr) {
            const int i = d0 / 2 + pr;
            float freq = (float)s * powf(10000.0f, -(float)i / 16.0f);
            float sn, c;
            sincosf(freq, &sn, &c);
            float x0 = q[2 * pr], x1 = q[2 * pr + 1];
            q[2 * pr]     = x0 * c - x1 * sn;
            q[2 * pr + 1] = x1 * c + x0 * sn;
            x0 = k[2 * pr]; x1 = k[2 * pr + 1];
            k[2 * pr]     = x0 * c - x1 * sn;
            k[2 * pr + 1] = x1 * c + x0 * sn;
        }
    }

    const int h = hh >> 1, j = hh & 1;
    const size_t obase = ((size_t)(b * H_ + h) * S_ + s) * 64 + d0;
    if (j == 0) {
        *(ushort4*)&q1[obase] = make_ushort4(f2bf(q[0]), f2bf(q[1]), f2bf(q[2]), f2bf(q[3]));
        *(ushort4*)&k1[obase] = make_ushort4(f2bf(k[0]), f2bf(k[1]), f2bf(k[2]), f2bf(k[3]));
    } else {
        float ssq_q = 0.f, ssq_k = 0.f;
#pragma unroll
        for (int i = 0; i < 4; ++i) {
            const float sg = sigmas[b * 64 + d0 + i];
            q[i] += sg; k[i] += sg;
            ssq_q += q[i] * q[i];
            ssq_k += k[i] * k[i];
        }
        for (int off = 1; off < 16; off <<= 1) {
            ssq_q += __shfl_xor(ssq_q, off, 16);
            ssq_k += __shfl_xor(ssq_k, off, 16);
        }
        const float rq = rsqrtf(ssq_q / 64.0f + 1e-8f);
        const float rk = rsqrtf(ssq_k / 64.0f + 1e-8f);
        float oq[4], ok[4];
#pragma unroll
        for (int i = 0; i < 4; ++i) {
            const float w = lnq_w[d0 + i], bb = lnq_b[d0 + i];
            oq[i] = q[i] * rq * w + bb;
            ok[i] = k[i] * rk * w + bb;
        }
        *(ushort4*)&q2n[obase] = make_ushort4(f2bf(oq[0]), f2bf(oq[1]), f2bf(oq[2]), f2bf(oq[3]));
        *(ushort4*)&k2n[obase] = make_ushort4(f2bf(ok[0]), f2bf(ok[1]), f2bf(ok[2]), f2bf(ok[3]));
    }
}

// ------------------------------------------------- softmax update (per wave, one branch)
__device__ __forceinline__ void sm_update(f32x4 (&s)[4], float (&m)[4], float (&lsum)[4],
                                          f32x4 (&o)[8], short* __restrict__ Pw,
                                          const bool diag, const int qr0, const int k0,
                                          const int lr, const int lg) {
    float nm[4];
#pragma unroll
    for (int r = 0; r < 4; ++r) nm[r] = m[r];
#pragma unroll
    for (int ks = 0; ks < 4; ++ks) {
#pragma unroll
        for (int r = 0; r < 4; ++r) {
            float v = s[ks][r];
            if (diag && (k0 + ks * 16 + lr > qr0 + r)) v = -INFINITY;
            else v *= 0.125f;
            s[ks][r] = v;
            nm[r] = fmaxf(nm[r], v);
        }
    }
#pragma unroll
    for (int r = 0; r < 4; ++r) {
        nm[r] = fmaxf(nm[r], __shfl_xor(nm[r], 1));
        nm[r] = fmaxf(nm[r], __shfl_xor(nm[r], 2));
        nm[r] = fmaxf(nm[r], __shfl_xor(nm[r], 4));
        nm[r] = fmaxf(nm[r], __shfl_xor(nm[r], 8));
    }
    float al[4], rs[4];
#pragma unroll
    for (int r = 0; r < 4; ++r) { al[r] = __expf(m[r] - nm[r]); m[r] = nm[r]; rs[r] = 0.f; }
#pragma unroll
    for (int ks = 0; ks < 4; ++ks) {
#pragma unroll
        for (int r = 0; r < 4; ++r) {
            float p = __expf(s[ks][r] - nm[r]);
            rs[r] += p;
            Pw[(lg * 4 + r) * 72 + ks * 16 + lr] = (short)f2bf(p);
        }
    }
#pragma unroll
    for (int r = 0; r < 4; ++r) {
        rs[r] += __shfl_xor(rs[r], 1);
        rs[r] += __shfl_xor(rs[r], 2);
        rs[r] += __shfl_xor(rs[r], 4);
        rs[r] += __shfl_xor(rs[r], 8);
        lsum[r] = lsum[r] * al[r] + rs[r];
    }
#pragma unroll
    for (int es = 0; es < 8; ++es) {
#pragma unroll
        for (int r = 0; r < 4; ++r) o[es][r] *= al[r];
    }
}

// ------------------------------------------------- dual attention, split-K partials
// grid: (32 = (15-qt)*2+part, H, B).  8 waves; QBLK=128 (wave = 16 rows); KVBLK=64.
// K1/K2/V^T tiles staged in LDS (vectorized, padded 72); P per-wave in LDS.
__global__ __launch_bounds__(512, 4) void attn_part(const short* __restrict__ q1g,
                                                    const short* __restrict__ q2g,
                                                    const short* __restrict__ k1g,
                                                    const short* __restrict__ k2g,
                                                    const short* __restrict__ vt,
                                                    short* __restrict__ pO0,
                                                    short* __restrict__ pO1,
                                                    float* __restrict__ pml) {
    __shared__ short Ks1[64 * 72];
    __shared__ short Ks2[64 * 72];
    __shared__ short Vt[128 * 72];
    __shared__ short Ps[8][16 * 72];   // per-wave P (reused across branches)

    const int bx = blockIdx.x;
    const int qt = 15 - (bx >> 1), part = bx & 1;   // LPT: big blocks first
    const int h = blockIdx.y, b = blockIdx.z, bh = b * H_ + h;
    const int q0 = qt * 128;
    const int t = threadIdx.x, w = t >> 6, l = t & 63;
    const int lr = l & 15, lg = l >> 4;

    const size_t kbase = (size_t)bh * S_ * 64;
    const size_t vbase = (size_t)bh * 128 * S_;

    // Q fragments (wave w owns rows q0 + w*16 .. +15)
    bf16x8 qa1[2], qa2[2];
    {
        const size_t rb = kbase + (size_t)(q0 + w * 16 + lr) * 64;
#pragma unroll
        for (int dh = 0; dh < 2; ++dh) {
            qa1[dh] = *(const bf16x8*)(q1g + rb + dh * 32 + lg * 8);
            qa2[dh] = *(const bf16x8*)(q2g + rb + dh * 32 + lg * 8);
        }
    }

    const int nkt = 2 * (qt + 1), mid = qt + 1;
    const int kt0 = part ? mid : 0, kt1 = part ? nkt : mid;

    float m1[4], m2[4], l1[4], l2[4];
#pragma unroll
    for (int r = 0; r < 4; ++r) { m1[r] = -1e30f; m2[r] = -1e30f; l1[r] = 0.f; l2[r] = 0.f; }
    f32x4 o1[8], o2[8];
#pragma unroll
    for (int es = 0; es < 8; ++es) { o1[es] = (f32x4){0.f,0.f,0.f,0.f}; o2[es] = (f32x4){0.f,0.f,0.f,0.f}; }

    short* Pw = &Ps[w][0];
    const int qr0 = q0 + w * 16 + lg * 4;
    const int wrow_lo = q0 + w * 16, wrow_hi = wrow_lo + 15;

    const int srow = t >> 3, scol = (t & 7) * 8;   // staging: 16B per thread per tile

    for (int kt = kt0; kt < kt1; ++kt) {
        const int k0 = kt * 64;
        __syncthreads();   // prior tile reads done
        // stage K1,K2 [64][72] and V^T [128][72] (vectorized 16B, coalesced)
        {
            const size_t g = kbase + (size_t)(k0 + srow) * 64 + scol;
            *(bf16x8*)(Ks1 + srow * 72 + scol) = *(const bf16x8*)(k1g + g);
            *(bf16x8*)(Ks2 + srow * 72 + scol) = *(const bf16x8*)(k2g + g);
            *(bf16x8*)(Vt + srow * 72 + scol) =
                *(const bf16x8*)(vt + vbase + (size_t)srow * S_ + k0 + scol);
            *(bf16x8*)(Vt + (srow + 64) * 72 + scol) =
                *(const bf16x8*)(vt + vbase + (size_t)(srow + 64) * S_ + k0 + scol);
        }
        __syncthreads();

        if (k0 > wrow_hi) continue;   // tile fully above this wave's diagonal
        const bool diag = (k0 + 63 > wrow_lo);

        // ---- branch 1
        {
            f32x4 s[4];
#pragma unroll
            for (int ks = 0; ks < 4; ++ks) s[ks] = (f32x4){0.f,0.f,0.f,0.f};
#pragma unroll
            for (int ks = 0; ks < 4; ++ks)
#pragma unroll
                for (int dh = 0; dh < 2; ++dh) {
                    bf16x8 kf = *(const bf16x8*)(Ks1 + (ks * 16 + lr) * 72 + dh * 32 + lg * 8);
                    s[ks] = __builtin_amdgcn_mfma_f32_16x16x32_bf16(qa1[dh], kf, s[ks], 0, 0, 0);
                }
            sm_update(s, m1, l1, o1, Pw, diag, qr0, k0, lr, lg);
#pragma unroll
            for (int kb = 0; kb < 2; ++kb) {
                bf16x8 pf = *(const bf16x8*)(Pw + lr * 72 + kb * 32 + lg * 8);
#pragma unroll
                for (int es = 0; es < 8; ++es) {
                    bf16x8 vf = *(const bf16x8*)(Vt + (es * 16 + lr) * 72 + kb * 32 + lg * 8);
                    o1[es] = __builtin_amdgcn_mfma_f32_16x16x32_bf16(pf, vf, o1[es], 0, 0, 0);
                }
            }
        }
        // ---- branch 2
        {
            f32x4 s[4];
#pragma unroll
            for (int ks = 0; ks < 4; ++ks) s[ks] = (f32x4){0.f,0.f,0.f,0.f};
#pragma unroll
            for (int ks = 0; ks < 4; ++ks)
#pragma unroll
                for (int dh = 0; dh < 2; ++dh) {
                    bf16x8 kf = *(const bf16x8*)(Ks2 + (ks * 16 + lr) * 72 + dh * 32 + lg * 8);
                    s[ks] = __builtin_amdgcn_mfma_f32_16x16x32_bf16(qa2[dh], kf, s[ks], 0, 0, 0);
                }
            sm_update(s, m2, l2, o2, Pw, diag, qr0, k0, lr, lg);
#pragma unroll
            for (int kb = 0; kb < 2; ++kb) {
                bf16x8 pf = *(const bf16x8*)(Pw + lr * 72 + kb * 32 + lg * 8);
#pragma unroll
                for (int es = 0; es < 8; ++es) {
                    bf16x8 vf = *(const bf16x8*)(Vt + (es * 16 + lr) * 72 + kb * 32 + lg * 8);
                    o2[es] = __builtin_amdgcn_mfma_f32_16x16x32_bf16(pf, vf, o2[es], 0, 0, 0);
                }
            }
        }
    }

    // store partials (O unnormalized, bf16; m,l f32)
    short* pO = part ? pO1 : pO0;
#pragma unroll
    for (int r = 0; r < 4; ++r) {
        const int q = q0 + w * 16 + lg * 4 + r;
        const size_t ob = ((size_t)bh * S_ + q) * 256;
#pragma unroll
        for (int es = 0; es < 8; ++es) {
            pO[ob + es * 16 + lr]       = (short)f2bf(o1[es][r]);
            pO[ob + 128 + es * 16 + lr] = (short)f2bf(o2[es][r]);
        }
    }
    if (lr == 0) {
#pragma unroll
        for (int r = 0; r < 4; ++r) {
            const int q = q0 + w * 16 + lg * 4 + r;
            float4 v = make_float4(m1[r], l1[r], m2[r], l2[r]);
            *(float4*)&pml[(((size_t)part * 16 + bh) * S_ + q) * 4] = v;
        }
    }
}

// ------------------------------------------------- combine partials + diff + RMSNorm
__global__ __launch_bounds__(256) void attn_combine(const short* __restrict__ pO0,
                                                    const short* __restrict__ pO1,
                                                    const float* __restrict__ pml,
                                                    const float* __restrict__ lamp,
                                                    const float* __restrict__ ln_w,
                                                    const float* __restrict__ ln_b,
                                                    short* __restrict__ arms) {
    const int tok = blockIdx.x;           // 0..4095
    const int b = tok >> 11, q = tok & 2047;
    const int t = threadIdx.x;
    const int h = t >> 5, ln32 = t & 31, e0 = ln32 * 4;
    const int bh = b * H_ + h;
    const float lam = lamp[0];

    float4 mla = *(const float4*)&pml[(((size_t)0 * 16 + bh) * S_ + q) * 4];
    float4 mlb = *(const float4*)&pml[(((size_t)1 * 16 + bh) * S_ + q) * 4];

    const float m1 = fmaxf(mla.x, mlb.x);
    const float aa1 = __expf(mla.x - m1), ab1 = __expf(mlb.x - m1);
    const float il1 = 1.0f / (aa1 * mla.y + ab1 * mlb.y);
    const float m2 = fmaxf(mla.z, mlb.z);
    const float aa2 = __expf(mla.z - m2), ab2 = __expf(mlb.z - m2);
    const float il2 = 1.0f / (aa2 * mla.w + ab2 * mlb.w);

    const size_t ob = ((size_t)bh * S_ + q) * 256;
    ushort4 oa1 = *(const ushort4*)&pO0[ob + e0];
    ushort4 ob1 = *(const ushort4*)&pO1[ob + e0];
    ushort4 oa2 = *(const ushort4*)&pO0[ob + 128 + e0];
    ushort4 ob2 = *(const ushort4*)&pO1[ob + 128 + e0];

    float comb[4]; float ssq = 0.f;
    {
        const unsigned short* a1 = (const unsigned short*)&oa1;
        const unsigned short* b1v = (const unsigned short*)&ob1;
        const unsigned short* a2 = (const unsigned short*)&oa2;
        const unsigned short* b2v = (const unsigned short*)&ob2;
#pragma unroll
        for (int i = 0; i < 4; ++i) {
            const float O1 = (aa1 * bf2f(a1[i]) + ab1 * bf2f(b1v[i])) * il1;
            const float O2 = (aa2 * bf2f(a2[i]) + ab2 * bf2f(b2v[i])) * il2;
            const float c = O1 - lam * O2;
            comb[i] = c; ssq += c * c;
        }
    }
    for (int off = 1; off < 32; off <<= 1) ssq += __shfl_xor(ssq, off, 32);
    const float rms = rsqrtf(ssq / 128.0f + 1e-8f);

    ushort4 o;
    unsigned short* op = (unsigned short*)&o;
#pragma unroll
    for (int i = 0; i < 4; ++i) {
        const int e = e0 + i;
        op[i] = f2bf((comb[i] * rms * ln_w[e] + ln_b[e]) * ONE_MINUS_LI);
    }
    *(ushort4*)&arms[(size_t)tok * 1024 + h * 128 + e0] = o;
}

// ---------------------------------------------------------------- add + LayerNorm
template <int WB>
__global__ __launch_bounds__(256) void add_ln_kernel(const float* __restrict__ X,
                                                     const float* __restrict__ Y,
                                                     const float* __restrict__ w,
                                                     const float* __restrict__ bvec,
                                                     float* __restrict__ out,
                                                     short* __restrict__ out_bf,
                                                     float eps) {
    const int row = blockIdx.x;
    const int t = threadIdx.x;
    __shared__ float red[4];

    float4 xv = *(const float4*)&X[(size_t)row * 1024 + t * 4];
    float4 yv = *(const float4*)&Y[(size_t)row * 1024 + t * 4];
    float v[4] = {xv.x + yv.x, xv.y + yv.y, xv.z + yv.z, xv.w + yv.w};

    float s = v[0] + v[1] + v[2] + v[3];
    for (int off = 1; off < 64; off <<= 1) s += __shfl_xor(s, off);
    if ((t & 63) == 0) red[t >> 6] = s;
    __syncthreads();
    const float mean = (red[0] + red[1] + red[2] + red[3]) * (1.0f / 1024.0f);

    float sq = 0.f;
#pragma unroll
    for (int i = 0; i < 4; ++i) { const float d = v[i] - mean; sq += d * d; }
    __syncthreads();
    for (int off = 1; off < 64; off <<= 1) sq += __shfl_xor(sq, off);
    if ((t & 63) == 0) red[t >> 6] = sq;
    __syncthreads();
    const float var = (red[0] + red[1] + red[2] + red[3]) * (1.0f / 1024.0f);
    const float rstd = rsqrtf(var + eps);

    float o[4];
#pragma unroll
    for (int i = 0; i < 4; ++i)
        o[i] = (v[i] - mean) * rstd * w[t * 4 + i] + bvec[t * 4 + i];
    *(float4*)&out[(size_t)row * 1024 + t * 4] = make_float4(o[0], o[1], o[2], o[3]);
    if (WB) {
        *(ushort4*)&out_bf[(size_t)row * 1024 + t * 4] =
            make_ushort4(f2bf(o[0]), f2bf(o[1]), f2bf(o[2]), f2bf(o[3]));
    }
}

// ---------------------------------------------------------------- launch
extern "C" void kernel_launch(void* const* d_in, const int* in_sizes, int n_in,
                              void* d_out, int out_size, void* d_ws, size_t ws_size,
                              hipStream_t stream) {
    const float* x      = (const float*)d_in[0];
    const float* sigmas = (const float*)d_in[1];
    const float* w_qkv  = (const float*)d_in[2];
    const float* w_out  = (const float*)d_in[3];
    const float* lq1    = (const float*)d_in[4];
    const float* lk1    = (const float*)d_in[5];
    const float* lq2    = (const float*)d_in[6];
    const float* lk2    = (const float*)d_in[7];
    const float* ln_w   = (const float*)d_in[8];
    const float* ln_b   = (const float*)d_in[9];
    const float* lnq_w  = (const float*)d_in[10];
    const float* lnq_b  = (const float*)d_in[11];
    const float* ln1_w  = (const float*)d_in[12];
    const float* ln1_b  = (const float*)d_in[13];
    const float* ln2_w  = (const float*)d_in[14];
    const float* ln2_b  = (const float*)d_in[15];
    const float* w1     = (const float*)d_in[16];
    const float* b1     = (const float*)d_in[17];
    const float* w2     = (const float*)d_in[18];
    const float* b2     = (const float*)d_in[19];

    char* ws = (char*)d_ws;
    short* x_bf    = (short*)(ws + 0);            //  8,388,608 (-> vt after qkv gemm)
    short* vt      = (short*)(ws + 0);            //  8,388,608 exactly
    short* w_qkvT  = (short*)(ws + 8388608);      //  6,291,456
    short* w_outT  = (short*)(ws + 14680064);     //  2,097,152
    short* w1T     = (short*)(ws + 16777216);     //  8,388,608
    short* w2T     = (short*)(ws + 25165824);     //  8,388,608
    short* qkv_bf  = (short*)(ws + 33554432);     // 25,165,824 (dead after rope+vtrans)
    short* pO0     = (short*)(ws + 33554432);     // 16,777,216
    float* pml     = (float*)(ws + 50331648);     //  1,048,576
    short* q1      = (short*)(ws + 58720256);     //  4,194,304
    short* q2n     = (short*)(ws + 62914560);
    short* k1      = (short*)(ws + 67108864);
    short* k2n     = (short*)(ws + 71303168);     // ends 75,497,472
    short* arms    = (short*)(ws + 75497472);     //  8,388,608
    short* pO1     = (short*)(ws + 83886080);     // 16,777,216 (-> a_f32 after combine)
    float* a_f32   = (float*)(ws + 83886080);
    float* h_f32   = (float*)(ws + 33554432);     // reuse pO0+pml region after combine
    short* h_bf    = (short*)(ws + 50331648);     //  8,388,608
    short* ffh     = (short*)(ws + 58720256);     // 33,554,432 (q/k + arms dead)
    float* ff      = (float*)(ws + 0);            // 16,777,216 (vt + w_qkvT dead)
    float* lam     = (float*)(ws + 100663296);

    // 1. lambda
    lam_kernel<<<1, 64, 0, stream>>>(lq1, lk1, lq2, lk2, lam);

    // 2. conversions
    convert_bf16<<<4096, 256, 0, stream>>>(x, x_bf);
    transpose_to_bf16<<<dim3(3072 / 32, 1024 / 32), 256, 0, stream>>>(w_qkv, w_qkvT, 1024, 3072);
    transpose_to_bf16<<<dim3(1024 / 32, 1024 / 32), 256, 0, stream>>>(w_out, w_outT, 1024, 1024);
    transpose_to_bf16<<<dim3(4096 / 32, 1024 / 32), 256, 0, stream>>>(w1, w1T, 1024, 4096);
    transpose_to_bf16<<<dim3(1024 / 32, 4096 / 32), 256, 0, stream>>>(w2, w2T, 4096, 1024);

    // 3. qkv = x @ w_qkv  -> bf16
    gemm_bt<0, 1><<<dim3(3072 / 128, 4096 / 128), 256, 0, stream>>>(x_bf, w_qkvT, nullptr,
                                                                    qkv_bf, NT_, 3072, 1024);

    // 4. rope + split + q2/k2 rmsnorm ; V transpose (x_bf dead now)
    rope_kernel<<<NT_, 256, 0, stream>>>(qkv_bf, sigmas, lnq_w, lnq_b, q1, q2n, k1, k2n);
    vtrans_kernel<<<dim3(S_ / 32, 4, 16), 256, 0, stream>>>(qkv_bf, vt);

    // 5. dual attention split-K partials + combine (qkv_bf dead after vtrans)
    attn_part<<<dim3(32, H_, B_), 512, 0, stream>>>(q1, q2n, k1, k2n, vt, pO0, pO1, pml);
    attn_combine<<<NT_, 256, 0, stream>>>(pO0, pO1, pml, lam, ln_w, ln_b, arms);

    // 6. a = arms @ w_out -> f32
    gemm_bt<0, 0><<<dim3(1024 / 128, 4096 / 128), 256, 0, stream>>>(arms, w_outT, nullptr,
                                                                    a_f32, NT_, 1024, 1024);

    // 7. h = LN(a + x) -> f32 + bf16
    add_ln_kernel<1><<<NT_, 256, 0, stream>>>(a_f32, x, ln1_w, ln1_b, h_f32, h_bf, 1e-5f);

    // 8. ffh = silu(h @ w1 + b1) -> bf16
    gemm_bt<2, 1><<<dim3(4096 / 128, 4096 / 128), 256, 0, stream>>>(h_bf, w1T, b1,
                                                                    ffh, NT_, 4096, 1024);

    // 9. ff = ffh @ w2 + b2 -> f32
    gemm_bt<1, 0><<<dim3(1024 / 128, 4096 / 128), 256, 0, stream>>>(ffh, w2T, b2,
                                                                    ff, NT_, 1024, 4096);

    // 10. out = LN(ff + h)
    add_ln_kernel<0><<<NT_, 256, 0, stream>>>(ff, h_f32, ln2_w, ln2_b, (float*)d_out,
                                              nullptr, 1e-5f);
}

// Round 5
// 431.560 us; speedup vs baseline: 1.3984x; 1.0253x over previous
//
#include <hip/hip_runtime.h>
#include <math.h>
#include <stdint.h>

#define B_ 2
#define S_ 2048
#define D_ 1024
#define H_ 8
#define NT_ (B_*S_)   // 4096 tokens

static constexpr float LAMBDA_INIT = 0.47071301834358415f;
static constexpr float ONE_MINUS_LI = 1.0f - 0.47071301834358415f;

typedef __attribute__((ext_vector_type(8))) short bf16x8;
typedef __attribute__((ext_vector_type(4))) float f32x4;

__device__ __forceinline__ unsigned short f2bf(float x) {
    union { float f; unsigned int u; } v; v.f = x;
    unsigned int r = v.u + 0x7fffu + ((v.u >> 16) & 1u);
    return (unsigned short)(r >> 16);
}
__device__ __forceinline__ float bf2f(unsigned short b) {
    union { unsigned int u; float f; } v; v.u = ((unsigned int)b) << 16;
    return v.f;
}

#define GLD16(gp, lp) __builtin_amdgcn_global_load_lds( \
    (const __attribute__((address_space(1))) void*)(gp), \
    (__attribute__((address_space(3))) void*)(lp), 16, 0, 0)

// ---------------------------------------------------------------- lam scalar
__global__ void lam_kernel(const float* __restrict__ lq1, const float* __restrict__ lk1,
                           const float* __restrict__ lq2, const float* __restrict__ lk2,
                           float* __restrict__ lam_out) {
    int t = threadIdx.x;  // 64 threads
    float p1 = lq1[t] * lk1[t];
    float p2 = lq2[t] * lk2[t];
    for (int off = 32; off; off >>= 1) {
        p1 += __shfl_xor(p1, off);
        p2 += __shfl_xor(p2, off);
    }
    if (t == 0) lam_out[0] = expf(p1) - expf(p2) + LAMBDA_INIT;
}

// ---------------------------------------------------------------- f32 -> bf16
__global__ __launch_bounds__(256) void convert_bf16(const float* __restrict__ in,
                                                    short* __restrict__ out) {
    const size_t i = ((size_t)blockIdx.x * 256 + threadIdx.x) * 4;
    float4 v = *(const float4*)(in + i);
    ushort4 o = make_ushort4(f2bf(v.x), f2bf(v.y), f2bf(v.z), f2bf(v.w));
    *(ushort4*)(out + i) = o;
}

// --------------------------------------------- transpose + convert W[K][N] -> WT[N][K]
__global__ __launch_bounds__(256) void transpose_to_bf16(const float* __restrict__ W,
                                                         short* __restrict__ WT,
                                                         int K, int N) {
    __shared__ float tile[32][33];
    const int t = threadIdx.x;
    const int k0 = blockIdx.y * 32, n0 = blockIdx.x * 32;
    const int r = t >> 3, c0 = (t & 7) * 4;
    float4 v = *(const float4*)(W + (size_t)(k0 + r) * N + n0 + c0);
    tile[r][c0 + 0] = v.x; tile[r][c0 + 1] = v.y;
    tile[r][c0 + 2] = v.z; tile[r][c0 + 3] = v.w;
    __syncthreads();
    ushort4 o = make_ushort4(f2bf(tile[c0 + 0][r]), f2bf(tile[c0 + 1][r]),
                             f2bf(tile[c0 + 2][r]), f2bf(tile[c0 + 3][r]));
    *(ushort4*)(WT + (size_t)(n0 + r) * K + k0 + c0) = o;
}

// --------------------------------------------- V transpose: qkv V part -> vt[bh][e][s]
__global__ __launch_bounds__(256) void vtrans_kernel(const short* __restrict__ qkv_bf,
                                                     short* __restrict__ vt) {
    __shared__ short tile[32][34];
    const int s0 = blockIdx.x * 32, e0 = blockIdx.y * 32, bh = blockIdx.z;
    const int b = bh >> 3, h = bh & 7;
    const int t = threadIdx.x, r = t >> 3, c0 = (t & 7) * 4;
    ushort4 v = *(const ushort4*)(qkv_bf + (size_t)(b * S_ + s0 + r) * 3072 + 2048 + h * 128 + e0 + c0);
    tile[r][c0 + 0] = v.x; tile[r][c0 + 1] = v.y;
    tile[r][c0 + 2] = v.z; tile[r][c0 + 3] = v.w;
    __syncthreads();
    ushort4 o = make_ushort4((unsigned short)tile[c0 + 0][r], (unsigned short)tile[c0 + 1][r],
                             (unsigned short)tile[c0 + 2][r], (unsigned short)tile[c0 + 3][r]);
    *(ushort4*)(vt + ((size_t)bh * 128 + e0 + r) * S_ + s0 + c0) = o;
}

// ---------------------------------------------------------------- bf16 MFMA GEMM
// C[M,N] = A[M,K] @ BT[N,K]^T.  128x128 tile, BK=32, 4 waves, 4x4 16x16 frags/wave.
template <int EPI, int OUTBF>
__global__ __launch_bounds__(256) void gemm_bt(const short* __restrict__ A,
                                               const short* __restrict__ BT,
                                               const float* __restrict__ bias,
                                               void* __restrict__ Cout,
                                               int M, int N, int K) {
    __shared__ short As[128 * 32];   // [row][k] 64B rows
    __shared__ short Bs[128 * 32];
    const int t = threadIdx.x;
    const int w = t >> 6, l = t & 63;
    const int lr = l & 15, lg = l >> 4;
    const int row0 = blockIdx.y * 128, col0 = blockIdx.x * 128;
    const int wr = (w >> 1) * 64, wc = (w & 1) * 64;

    f32x4 acc[4][4];
#pragma unroll
    for (int i = 0; i < 4; ++i)
#pragma unroll
        for (int j = 0; j < 4; ++j) acc[i][j] = (f32x4){0.f, 0.f, 0.f, 0.f};

    const short* Ag = A + (size_t)(row0 + w * 32 + (l >> 2)) * K + (l & 3) * 8;
    const short* Bg = BT + (size_t)(col0 + w * 32 + (l >> 2)) * K + (l & 3) * 8;

    for (int k0 = 0; k0 < K; k0 += 32) {
        __syncthreads();
#pragma unroll
        for (int j = 0; j < 2; ++j) {
            GLD16(Ag + k0 + (size_t)j * 16 * K, As + (w * 2 + j) * 512);
            GLD16(Bg + k0 + (size_t)j * 16 * K, Bs + (w * 2 + j) * 512);
        }
        __syncthreads();

        bf16x8 af[4], bfr[4];
#pragma unroll
        for (int i = 0; i < 4; ++i)
            af[i] = *(const bf16x8*)(As + (wr + i * 16 + lr) * 32 + lg * 8);
#pragma unroll
        for (int j = 0; j < 4; ++j)
            bfr[j] = *(const bf16x8*)(Bs + (wc + j * 16 + lr) * 32 + lg * 8);
#pragma unroll
        for (int i = 0; i < 4; ++i)
#pragma unroll
            for (int j = 0; j < 4; ++j)
                acc[i][j] = __builtin_amdgcn_mfma_f32_16x16x32_bf16(af[i], bfr[j], acc[i][j], 0, 0, 0);
    }

#pragma unroll
    for (int i = 0; i < 4; ++i) {
#pragma unroll
        for (int j = 0; j < 4; ++j) {
            const int col = col0 + wc + j * 16 + lr;
            float bcol = (EPI >= 1) ? bias[col] : 0.f;
#pragma unroll
            for (int r = 0; r < 4; ++r) {
                const int row = row0 + wr + i * 16 + lg * 4 + r;
                float v = acc[i][j][r];
                if (EPI >= 1) v += bcol;
                if (EPI == 2) v = v / (1.0f + expf(-v));
                if (OUTBF) ((short*)Cout)[(size_t)row * N + col] = (short)f2bf(v);
                else       ((float*)Cout)[(size_t)row * N + col] = v;
            }
        }
    }
}

// ------------------------------------------------- RoPE + split + q2/k2 RMSNorm (bf16 io)
__global__ __launch_bounds__(256) void rope_kernel(const short* __restrict__ qkv,
                                                   const float* __restrict__ sigmas,
                                                   const float* __restrict__ lnq_w,
                                                   const float* __restrict__ lnq_b,
                                                   short* __restrict__ q1, short* __restrict__ q2n,
                                                   short* __restrict__ k1, short* __restrict__ k2n) {
    const int tok = blockIdx.x;            // 0..4095
    const int b = tok >> 11, s = tok & 2047;
    const int t = threadIdx.x;
    const int hh = t >> 4;                 // 0..15 (head in 2H layout)
    const int d0 = (t & 15) * 4;

    const short* qrow = qkv + (size_t)tok * 3072 + hh * 64 + d0;
    ushort4 qv = *(const ushort4*)qrow;
    ushort4 kv = *(const ushort4*)(qrow + 1024);
    float q[4] = {bf2f(qv.x), bf2f(qv.y), bf2f(qv.z), bf2f(qv.w)};
    float k[4] = {bf2f(kv.x), bf2f(kv.y), bf2f(kv.z), bf2f(kv.w)};

    if (d0 < 32) {
#pragma unroll
        for (int pr = 0; pr < 2; ++pr) {
            const int i = d0 / 2 + pr;
            float freq = (float)s * powf(10000.0f, -(float)i / 16.0f);
            float sn, c;
            sincosf(freq, &sn, &c);
            float x0 = q[2 * pr], x1 = q[2 * pr + 1];
            q[2 * pr]     = x0 * c - x1 * sn;
            q[2 * pr + 1] = x1 * c + x0 * sn;
            x0 = k[2 * pr]; x1 = k[2 * pr + 1];
            k[2 * pr]     = x0 * c - x1 * sn;
            k[2 * pr + 1] = x1 * c + x0 * sn;
        }
    }

    const int h = hh >> 1, j = hh & 1;
    const size_t obase = ((size_t)(b * H_ + h) * S_ + s) * 64 + d0;
    if (j == 0) {
        *(ushort4*)&q1[obase] = make_ushort4(f2bf(q[0]), f2bf(q[1]), f2bf(q[2]), f2bf(q[3]));
        *(ushort4*)&k1[obase] = make_ushort4(f2bf(k[0]), f2bf(k[1]), f2bf(k[2]), f2bf(k[3]));
    } else {
        float ssq_q = 0.f, ssq_k = 0.f;
#pragma unroll
        for (int i = 0; i < 4; ++i) {
            const float sg = sigmas[b * 64 + d0 + i];
            q[i] += sg; k[i] += sg;
            ssq_q += q[i] * q[i];
            ssq_k += k[i] * k[i];
        }
        for (int off = 1; off < 16; off <<= 1) {
            ssq_q += __shfl_xor(ssq_q, off, 16);
            ssq_k += __shfl_xor(ssq_k, off, 16);
        }
        const float rq = rsqrtf(ssq_q / 64.0f + 1e-8f);
        const float rk = rsqrtf(ssq_k / 64.0f + 1e-8f);
        float oq[4], ok[4];
#pragma unroll
        for (int i = 0; i < 4; ++i) {
            const float w = lnq_w[d0 + i], bb = lnq_b[d0 + i];
            oq[i] = q[i] * rq * w + bb;
            ok[i] = k[i] * rk * w + bb;
        }
        *(ushort4*)&q2n[obase] = make_ushort4(f2bf(oq[0]), f2bf(oq[1]), f2bf(oq[2]), f2bf(oq[3]));
        *(ushort4*)&k2n[obase] = make_ushort4(f2bf(ok[0]), f2bf(ok[1]), f2bf(ok[2]), f2bf(ok[3]));
    }
}

// ------------------------------------------------- softmax update (per wave, one branch)
__device__ __forceinline__ void sm_update(f32x4 (&s)[4], float (&m)[4], float (&lsum)[4],
                                          f32x4 (&o)[8], short* __restrict__ Pw,
                                          const bool diag, const int qr0, const int k0,
                                          const int lr, const int lg) {
    float nm[4];
#pragma unroll
    for (int r = 0; r < 4; ++r) nm[r] = m[r];
#pragma unroll
    for (int ks = 0; ks < 4; ++ks) {
#pragma unroll
        for (int r = 0; r < 4; ++r) {
            float v = s[ks][r];
            if (diag && (k0 + ks * 16 + lr > qr0 + r)) v = -INFINITY;
            else v *= 0.125f;
            s[ks][r] = v;
            nm[r] = fmaxf(nm[r], v);
        }
    }
#pragma unroll
    for (int r = 0; r < 4; ++r) {
        nm[r] = fmaxf(nm[r], __shfl_xor(nm[r], 1));
        nm[r] = fmaxf(nm[r], __shfl_xor(nm[r], 2));
        nm[r] = fmaxf(nm[r], __shfl_xor(nm[r], 4));
        nm[r] = fmaxf(nm[r], __shfl_xor(nm[r], 8));
    }
    float al[4], rs[4];
#pragma unroll
    for (int r = 0; r < 4; ++r) { al[r] = __expf(m[r] - nm[r]); m[r] = nm[r]; rs[r] = 0.f; }
#pragma unroll
    for (int ks = 0; ks < 4; ++ks) {
#pragma unroll
        for (int r = 0; r < 4; ++r) {
            float p = __expf(s[ks][r] - nm[r]);
            rs[r] += p;
            Pw[(lg * 4 + r) * 72 + ks * 16 + lr] = (short)f2bf(p);
        }
    }
#pragma unroll
    for (int r = 0; r < 4; ++r) {
        rs[r] += __shfl_xor(rs[r], 1);
        rs[r] += __shfl_xor(rs[r], 2);
        rs[r] += __shfl_xor(rs[r], 4);
        rs[r] += __shfl_xor(rs[r], 8);
        lsum[r] = lsum[r] * al[r] + rs[r];
    }
#pragma unroll
    for (int es = 0; es < 8; ++es) {
#pragma unroll
        for (int r = 0; r < 4; ++r) o[es][r] *= al[r];
    }
}

// ------------------------------------------------- dual attention, split-K partials
// 1D grid of 512, XCD-locality swizzled: each XCD owns 2 bh (all 32 of a bh's
// blocks share one per-XCD L2 -> K/V/Q panels fetched from HBM once, not 8x).
// 8 waves; QBLK=128 (wave = 16 rows); KVBLK=64. K1/K2/V^T staged in LDS.
__global__ __launch_bounds__(512, 4) void attn_part(const short* __restrict__ q1g,
                                                    const short* __restrict__ q2g,
                                                    const short* __restrict__ k1g,
                                                    const short* __restrict__ k2g,
                                                    const short* __restrict__ vt,
                                                    short* __restrict__ pO0,
                                                    short* __restrict__ pO1,
                                                    float* __restrict__ pml) {
    __shared__ short Ks1[64 * 72];
    __shared__ short Ks2[64 * 72];
    __shared__ short Vt[128 * 72];
    __shared__ short Ps[8][16 * 72];   // per-wave P (reused across branches)

    // XCD swizzle: wg i lands on XCD i%8 (round-robin). Invert so each XCD
    // owns 2 consecutive bh; LPT (big qt first) preserved within each bh.
    const int i = blockIdx.x;            // 0..511
    const int xcd = i & 7, slot = i >> 3;
    const int bh = xcd * 2 + (slot >> 5);
    const int j = slot & 31;
    const int qt = 15 - (j >> 1), part = j & 1;
    const int h = bh & 7, b = bh >> 3;
    const int q0 = qt * 128;
    const int t = threadIdx.x, w = t >> 6, l = t & 63;
    const int lr = l & 15, lg = l >> 4;

    const size_t kbase = (size_t)bh * S_ * 64;
    const size_t vbase = (size_t)bh * 128 * S_;

    // Q fragments (wave w owns rows q0 + w*16 .. +15)
    bf16x8 qa1[2], qa2[2];
    {
        const size_t rb = kbase + (size_t)(q0 + w * 16 + lr) * 64;
#pragma unroll
        for (int dh = 0; dh < 2; ++dh) {
            qa1[dh] = *(const bf16x8*)(q1g + rb + dh * 32 + lg * 8);
            qa2[dh] = *(const bf16x8*)(q2g + rb + dh * 32 + lg * 8);
        }
    }

    const int nkt = 2 * (qt + 1), mid = qt + 1;
    const int kt0 = part ? mid : 0, kt1 = part ? nkt : mid;

    float m1[4], m2[4], l1[4], l2[4];
#pragma unroll
    for (int r = 0; r < 4; ++r) { m1[r] = -1e30f; m2[r] = -1e30f; l1[r] = 0.f; l2[r] = 0.f; }
    f32x4 o1[8], o2[8];
#pragma unroll
    for (int es = 0; es < 8; ++es) { o1[es] = (f32x4){0.f,0.f,0.f,0.f}; o2[es] = (f32x4){0.f,0.f,0.f,0.f}; }

    short* Pw = &Ps[w][0];
    const int qr0 = q0 + w * 16 + lg * 4;
    const int wrow_lo = q0 + w * 16, wrow_hi = wrow_lo + 15;

    const int srow = t >> 3, scol = (t & 7) * 8;   // staging: 16B per thread per tile

    for (int kt = kt0; kt < kt1; ++kt) {
        const int k0 = kt * 64;
        __syncthreads();   // prior tile reads done
        // stage K1,K2 [64][72] and V^T [128][72] (vectorized 16B, coalesced)
        {
            const size_t g = kbase + (size_t)(k0 + srow) * 64 + scol;
            *(bf16x8*)(Ks1 + srow * 72 + scol) = *(const bf16x8*)(k1g + g);
            *(bf16x8*)(Ks2 + srow * 72 + scol) = *(const bf16x8*)(k2g + g);
            *(bf16x8*)(Vt + srow * 72 + scol) =
                *(const bf16x8*)(vt + vbase + (size_t)srow * S_ + k0 + scol);
            *(bf16x8*)(Vt + (srow + 64) * 72 + scol) =
                *(const bf16x8*)(vt + vbase + (size_t)(srow + 64) * S_ + k0 + scol);
        }
        __syncthreads();

        if (k0 > wrow_hi) continue;   // tile fully above this wave's diagonal
        const bool diag = (k0 + 63 > wrow_lo);

        // ---- branch 1
        {
            f32x4 s[4];
#pragma unroll
            for (int ks = 0; ks < 4; ++ks) s[ks] = (f32x4){0.f,0.f,0.f,0.f};
#pragma unroll
            for (int ks = 0; ks < 4; ++ks)
#pragma unroll
                for (int dh = 0; dh < 2; ++dh) {
                    bf16x8 kf = *(const bf16x8*)(Ks1 + (ks * 16 + lr) * 72 + dh * 32 + lg * 8);
                    s[ks] = __builtin_amdgcn_mfma_f32_16x16x32_bf16(qa1[dh], kf, s[ks], 0, 0, 0);
                }
            sm_update(s, m1, l1, o1, Pw, diag, qr0, k0, lr, lg);
#pragma unroll
            for (int kb = 0; kb < 2; ++kb) {
                bf16x8 pf = *(const bf16x8*)(Pw + lr * 72 + kb * 32 + lg * 8);
#pragma unroll
                for (int es = 0; es < 8; ++es) {
                    bf16x8 vf = *(const bf16x8*)(Vt + (es * 16 + lr) * 72 + kb * 32 + lg * 8);
                    o1[es] = __builtin_amdgcn_mfma_f32_16x16x32_bf16(pf, vf, o1[es], 0, 0, 0);
                }
            }
        }
        // ---- branch 2
        {
            f32x4 s[4];
#pragma unroll
            for (int ks = 0; ks < 4; ++ks) s[ks] = (f32x4){0.f,0.f,0.f,0.f};
#pragma unroll
            for (int ks = 0; ks < 4; ++ks)
#pragma unroll
                for (int dh = 0; dh < 2; ++dh) {
                    bf16x8 kf = *(const bf16x8*)(Ks2 + (ks * 16 + lr) * 72 + dh * 32 + lg * 8);
                    s[ks] = __builtin_amdgcn_mfma_f32_16x16x32_bf16(qa2[dh], kf, s[ks], 0, 0, 0);
                }
            sm_update(s, m2, l2, o2, Pw, diag, qr0, k0, lr, lg);
#pragma unroll
            for (int kb = 0; kb < 2; ++kb) {
                bf16x8 pf = *(const bf16x8*)(Pw + lr * 72 + kb * 32 + lg * 8);
#pragma unroll
                for (int es = 0; es < 8; ++es) {
                    bf16x8 vf = *(const bf16x8*)(Vt + (es * 16 + lr) * 72 + kb * 32 + lg * 8);
                    o2[es] = __builtin_amdgcn_mfma_f32_16x16x32_bf16(pf, vf, o2[es], 0, 0, 0);
                }
            }
        }
    }

    // store partials (O unnormalized, bf16; m,l f32)
    short* pO = part ? pO1 : pO0;
#pragma unroll
    for (int r = 0; r < 4; ++r) {
        const int q = q0 + w * 16 + lg * 4 + r;
        const size_t ob = ((size_t)bh * S_ + q) * 256;
#pragma unroll
        for (int es = 0; es < 8; ++es) {
            pO[ob + es * 16 + lr]       = (short)f2bf(o1[es][r]);
            pO[ob + 128 + es * 16 + lr] = (short)f2bf(o2[es][r]);
        }
    }
    if (lr == 0) {
#pragma unroll
        for (int r = 0; r < 4; ++r) {
            const int q = q0 + w * 16 + lg * 4 + r;
            float4 v = make_float4(m1[r], l1[r], m2[r], l2[r]);
            *(float4*)&pml[(((size_t)part * 16 + bh) * S_ + q) * 4] = v;
        }
    }
}

// ------------------------------------------------- combine partials + diff + RMSNorm
__global__ __launch_bounds__(256) void attn_combine(const short* __restrict__ pO0,
                                                    const short* __restrict__ pO1,
                                                    const float* __restrict__ pml,
                                                    const float* __restrict__ lamp,
                                                    const float* __restrict__ ln_w,
                                                    const float* __restrict__ ln_b,
                                                    short* __restrict__ arms) {
    const int tok = blockIdx.x;           // 0..4095
    const int b = tok >> 11, q = tok & 2047;
    const int t = threadIdx.x;
    const int h = t >> 5, ln32 = t & 31, e0 = ln32 * 4;
    const int bh = b * H_ + h;
    const float lam = lamp[0];

    float4 mla = *(const float4*)&pml[(((size_t)0 * 16 + bh) * S_ + q) * 4];
    float4 mlb = *(const float4*)&pml[(((size_t)1 * 16 + bh) * S_ + q) * 4];

    const float m1 = fmaxf(mla.x, mlb.x);
    const float aa1 = __expf(mla.x - m1), ab1 = __expf(mlb.x - m1);
    const float il1 = 1.0f / (aa1 * mla.y + ab1 * mlb.y);
    const float m2 = fmaxf(mla.z, mlb.z);
    const float aa2 = __expf(mla.z - m2), ab2 = __expf(mlb.z - m2);
    const float il2 = 1.0f / (aa2 * mla.w + ab2 * mlb.w);

    const size_t ob = ((size_t)bh * S_ + q) * 256;
    ushort4 oa1 = *(const ushort4*)&pO0[ob + e0];
    ushort4 ob1 = *(const ushort4*)&pO1[ob + e0];
    ushort4 oa2 = *(const ushort4*)&pO0[ob + 128 + e0];
    ushort4 ob2 = *(const ushort4*)&pO1[ob + 128 + e0];

    float comb[4]; float ssq = 0.f;
    {
        const unsigned short* a1 = (const unsigned short*)&oa1;
        const unsigned short* b1v = (const unsigned short*)&ob1;
        const unsigned short* a2 = (const unsigned short*)&oa2;
        const unsigned short* b2v = (const unsigned short*)&ob2;
#pragma unroll
        for (int i = 0; i < 4; ++i) {
            const float O1 = (aa1 * bf2f(a1[i]) + ab1 * bf2f(b1v[i])) * il1;
            const float O2 = (aa2 * bf2f(a2[i]) + ab2 * bf2f(b2v[i])) * il2;
            const float c = O1 - lam * O2;
            comb[i] = c; ssq += c * c;
        }
    }
    for (int off = 1; off < 32; off <<= 1) ssq += __shfl_xor(ssq, off, 32);
    const float rms = rsqrtf(ssq / 128.0f + 1e-8f);

    ushort4 o;
    unsigned short* op = (unsigned short*)&o;
#pragma unroll
    for (int i = 0; i < 4; ++i) {
        const int e = e0 + i;
        op[i] = f2bf((comb[i] * rms * ln_w[e] + ln_b[e]) * ONE_MINUS_LI);
    }
    *(ushort4*)&arms[(size_t)tok * 1024 + h * 128 + e0] = o;
}

// ---------------------------------------------------------------- add + LayerNorm
template <int WB>
__global__ __launch_bounds__(256) void add_ln_kernel(const float* __restrict__ X,
                                                     const float* __restrict__ Y,
                                                     const float* __restrict__ w,
                                                     const float* __restrict__ bvec,
                                                     float* __restrict__ out,
                                                     short* __restrict__ out_bf,
                                                     float eps) {
    const int row = blockIdx.x;
    const int t = threadIdx.x;
    __shared__ float red[4];

    float4 xv = *(const float4*)&X[(size_t)row * 1024 + t * 4];
    float4 yv = *(const float4*)&Y[(size_t)row * 1024 + t * 4];
    float v[4] = {xv.x + yv.x, xv.y + yv.y, xv.z + yv.z, xv.w + yv.w};

    float s = v[0] + v[1] + v[2] + v[3];
    for (int off = 1; off < 64; off <<= 1) s += __shfl_xor(s, off);
    if ((t & 63) == 0) red[t >> 6] = s;
    __syncthreads();
    const float mean = (red[0] + red[1] + red[2] + red[3]) * (1.0f / 1024.0f);

    float sq = 0.f;
#pragma unroll
    for (int i = 0; i < 4; ++i) { const float d = v[i] - mean; sq += d * d; }
    __syncthreads();
    for (int off = 1; off < 64; off <<= 1) sq += __shfl_xor(sq, off);
    if ((t & 63) == 0) red[t >> 6] = sq;
    __syncthreads();
    const float var = (red[0] + red[1] + red[2] + red[3]) * (1.0f / 1024.0f);
    const float rstd = rsqrtf(var + eps);

    float o[4];
#pragma unroll
    for (int i = 0; i < 4; ++i)
        o[i] = (v[i] - mean) * rstd * w[t * 4 + i] + bvec[t * 4 + i];
    *(float4*)&out[(size_t)row * 1024 + t * 4] = make_float4(o[0], o[1], o[2], o[3]);
    if (WB) {
        *(ushort4*)&out_bf[(size_t)row * 1024 + t * 4] =
            make_ushort4(f2bf(o[0]), f2bf(o[1]), f2bf(o[2]), f2bf(o[3]));
    }
}

// ---------------------------------------------------------------- launch
extern "C" void kernel_launch(void* const* d_in, const int* in_sizes, int n_in,
                              void* d_out, int out_size, void* d_ws, size_t ws_size,
                              hipStream_t stream) {
    const float* x      = (const float*)d_in[0];
    const float* sigmas = (const float*)d_in[1];
    const float* w_qkv  = (const float*)d_in[2];
    const float* w_out  = (const float*)d_in[3];
    const float* lq1    = (const float*)d_in[4];
    const float* lk1    = (const float*)d_in[5];
    const float* lq2    = (const float*)d_in[6];
    const float* lk2    = (const float*)d_in[7];
    const float* ln_w   = (const float*)d_in[8];
    const float* ln_b   = (const float*)d_in[9];
    const float* lnq_w  = (const float*)d_in[10];
    const float* lnq_b  = (const float*)d_in[11];
    const float* ln1_w  = (const float*)d_in[12];
    const float* ln1_b  = (const float*)d_in[13];
    const float* ln2_w  = (const float*)d_in[14];
    const float* ln2_b  = (const float*)d_in[15];
    const float* w1     = (const float*)d_in[16];
    const float* b1     = (const float*)d_in[17];
    const float* w2     = (const float*)d_in[18];
    const float* b2     = (const float*)d_in[19];

    char* ws = (char*)d_ws;
    short* x_bf    = (short*)(ws + 0);            //  8,388,608 (-> vt after qkv gemm)
    short* vt      = (short*)(ws + 0);            //  8,388,608 exactly
    short* w_qkvT  = (short*)(ws + 8388608);      //  6,291,456
    short* w_outT  = (short*)(ws + 14680064);     //  2,097,152
    short* w1T     = (short*)(ws + 16777216);     //  8,388,608
    short* w2T     = (short*)(ws + 25165824);     //  8,388,608
    short* qkv_bf  = (short*)(ws + 33554432);     // 25,165,824 (dead after rope+vtrans)
    short* pO0     = (short*)(ws + 33554432);     // 16,777,216
    float* pml     = (float*)(ws + 50331648);     //  1,048,576
    short* q1      = (short*)(ws + 58720256);     //  4,194,304
    short* q2n     = (short*)(ws + 62914560);
    short* k1      = (short*)(ws + 67108864);
    short* k2n     = (short*)(ws + 71303168);     // ends 75,497,472
    short* arms    = (short*)(ws + 75497472);     //  8,388,608
    short* pO1     = (short*)(ws + 83886080);     // 16,777,216 (-> a_f32 after combine)
    float* a_f32   = (float*)(ws + 83886080);
    float* h_f32   = (float*)(ws + 33554432);     // reuse pO0+pml region after combine
    short* h_bf    = (short*)(ws + 50331648);     //  8,388,608
    short* ffh     = (short*)(ws + 58720256);     // 33,554,432 (q/k + arms dead)
    float* ff      = (float*)(ws + 0);            // 16,777,216 (vt + w_qkvT dead)
    float* lam     = (float*)(ws + 100663296);

    // 1. lambda
    lam_kernel<<<1, 64, 0, stream>>>(lq1, lk1, lq2, lk2, lam);

    // 2. conversions
    convert_bf16<<<4096, 256, 0, stream>>>(x, x_bf);
    transpose_to_bf16<<<dim3(3072 / 32, 1024 / 32), 256, 0, stream>>>(w_qkv, w_qkvT, 1024, 3072);
    transpose_to_bf16<<<dim3(1024 / 32, 1024 / 32), 256, 0, stream>>>(w_out, w_outT, 1024, 1024);
    transpose_to_bf16<<<dim3(4096 / 32, 1024 / 32), 256, 0, stream>>>(w1, w1T, 1024, 4096);
    transpose_to_bf16<<<dim3(1024 / 32, 4096 / 32), 256, 0, stream>>>(w2, w2T, 4096, 1024);

    // 3. qkv = x @ w_qkv  -> bf16
    gemm_bt<0, 1><<<dim3(3072 / 128, 4096 / 128), 256, 0, stream>>>(x_bf, w_qkvT, nullptr,
                                                                    qkv_bf, NT_, 3072, 1024);

    // 4. rope + split + q2/k2 rmsnorm ; V transpose (x_bf dead now)
    rope_kernel<<<NT_, 256, 0, stream>>>(qkv_bf, sigmas, lnq_w, lnq_b, q1, q2n, k1, k2n);
    vtrans_kernel<<<dim3(S_ / 32, 4, 16), 256, 0, stream>>>(qkv_bf, vt);

    // 5. dual attention split-K partials (XCD-swizzled 1D grid) + combine
    attn_part<<<512, 512, 0, stream>>>(q1, q2n, k1, k2n, vt, pO0, pO1, pml);
    attn_combine<<<NT_, 256, 0, stream>>>(pO0, pO1, pml, lam, ln_w, ln_b, arms);

    // 6. a = arms @ w_out -> f32
    gemm_bt<0, 0><<<dim3(1024 / 128, 4096 / 128), 256, 0, stream>>>(arms, w_outT, nullptr,
                                                                    a_f32, NT_, 1024, 1024);

    // 7. h = LN(a + x) -> f32 + bf16
    add_ln_kernel<1><<<NT_, 256, 0, stream>>>(a_f32, x, ln1_w, ln1_b, h_f32, h_bf, 1e-5f);

    // 8. ffh = silu(h @ w1 + b1) -> bf16
    gemm_bt<2, 1><<<dim3(4096 / 128, 4096 / 128), 256, 0, stream>>>(h_bf, w1T, b1,
                                                                    ffh, NT_, 4096, 1024);

    // 9. ff = ffh @ w2 + b2 -> f32
    gemm_bt<1, 0><<<dim3(1024 / 128, 4096 / 128), 256, 0, stream>>>(ffh, w2T, b2,
                                                                    ff, NT_, 1024, 4096);

    // 10. out = LN(ff + h)
    add_ln_kernel<0><<<NT_, 256, 0, stream>>>(ff, h_f32, ln2_w, ln2_b, (float*)d_out,
                                              nullptr, 1e-5f);
}

// Round 6
// 428.291 us; speedup vs baseline: 1.4090x; 1.0076x over previous
//
#include <hip/hip_runtime.h>
#include <math.h>
#include <stdint.h>

#define B_ 2
#define S_ 2048
#define D_ 1024
#define H_ 8
#define NT_ (B_*S_)   // 4096 tokens

static constexpr float LAMBDA_INIT = 0.47071301834358415f;
static constexpr float ONE_MINUS_LI = 1.0f - 0.47071301834358415f;

typedef __attribute__((ext_vector_type(8))) short bf16x8;
typedef __attribute__((ext_vector_type(4))) float f32x4;

__device__ __forceinline__ unsigned short f2bf(float x) {
    union { float f; unsigned int u; } v; v.f = x;
    unsigned int r = v.u + 0x7fffu + ((v.u >> 16) & 1u);
    return (unsigned short)(r >> 16);
}
__device__ __forceinline__ float bf2f(unsigned short b) {
    union { unsigned int u; float f; } v; v.u = ((unsigned int)b) << 16;
    return v.f;
}

#define GLD16(gp, lp) __builtin_amdgcn_global_load_lds( \
    (const __attribute__((address_space(1))) void*)(gp), \
    (__attribute__((address_space(3))) void*)(lp), 16, 0, 0)

// ---------------------------------------------------------------- lam scalar
__global__ void lam_kernel(const float* __restrict__ lq1, const float* __restrict__ lk1,
                           const float* __restrict__ lq2, const float* __restrict__ lk2,
                           float* __restrict__ lam_out) {
    int t = threadIdx.x;  // 64 threads
    float p1 = lq1[t] * lk1[t];
    float p2 = lq2[t] * lk2[t];
    for (int off = 32; off; off >>= 1) {
        p1 += __shfl_xor(p1, off);
        p2 += __shfl_xor(p2, off);
    }
    if (t == 0) lam_out[0] = expf(p1) - expf(p2) + LAMBDA_INIT;
}

// ---------------------------------------------------------------- f32 -> bf16
__global__ __launch_bounds__(256) void convert_bf16(const float* __restrict__ in,
                                                    short* __restrict__ out) {
    const size_t i = ((size_t)blockIdx.x * 256 + threadIdx.x) * 4;
    float4 v = *(const float4*)(in + i);
    ushort4 o = make_ushort4(f2bf(v.x), f2bf(v.y), f2bf(v.z), f2bf(v.w));
    *(ushort4*)(out + i) = o;
}

// --------------------------------------------- transpose + convert W[K][N] -> WT[N][K]
__global__ __launch_bounds__(256) void transpose_to_bf16(const float* __restrict__ W,
                                                         short* __restrict__ WT,
                                                         int K, int N) {
    __shared__ float tile[32][33];
    const int t = threadIdx.x;
    const int k0 = blockIdx.y * 32, n0 = blockIdx.x * 32;
    const int r = t >> 3, c0 = (t & 7) * 4;
    float4 v = *(const float4*)(W + (size_t)(k0 + r) * N + n0 + c0);
    tile[r][c0 + 0] = v.x; tile[r][c0 + 1] = v.y;
    tile[r][c0 + 2] = v.z; tile[r][c0 + 3] = v.w;
    __syncthreads();
    ushort4 o = make_ushort4(f2bf(tile[c0 + 0][r]), f2bf(tile[c0 + 1][r]),
                             f2bf(tile[c0 + 2][r]), f2bf(tile[c0 + 3][r]));
    *(ushort4*)(WT + (size_t)(n0 + r) * K + k0 + c0) = o;
}

// --------------------------------------------- V transpose: qkv V part -> vt[bh][e][s]
__global__ __launch_bounds__(256) void vtrans_kernel(const short* __restrict__ qkv_bf,
                                                     short* __restrict__ vt) {
    __shared__ short tile[32][34];
    const int s0 = blockIdx.x * 32, e0 = blockIdx.y * 32, bh = blockIdx.z;
    const int b = bh >> 3, h = bh & 7;
    const int t = threadIdx.x, r = t >> 3, c0 = (t & 7) * 4;
    ushort4 v = *(const ushort4*)(qkv_bf + (size_t)(b * S_ + s0 + r) * 3072 + 2048 + h * 128 + e0 + c0);
    tile[r][c0 + 0] = v.x; tile[r][c0 + 1] = v.y;
    tile[r][c0 + 2] = v.z; tile[r][c0 + 3] = v.w;
    __syncthreads();
    ushort4 o = make_ushort4((unsigned short)tile[c0 + 0][r], (unsigned short)tile[c0 + 1][r],
                             (unsigned short)tile[c0 + 2][r], (unsigned short)tile[c0 + 3][r]);
    *(ushort4*)(vt + ((size_t)bh * 128 + e0 + r) * S_ + s0 + c0) = o;
}

// ---------------------------------------------------------------- bf16 MFMA GEMM
// C[M,N] = A[M,K] @ BT[N,K]^T.  128x128 tile, BK=32, 4 waves, 4x4 16x16 frags/wave.
template <int EPI, int OUTBF>
__global__ __launch_bounds__(256) void gemm_bt(const short* __restrict__ A,
                                               const short* __restrict__ BT,
                                               const float* __restrict__ bias,
                                               void* __restrict__ Cout,
                                               int M, int N, int K) {
    __shared__ short As[128 * 32];   // [row][k] 64B rows
    __shared__ short Bs[128 * 32];
    const int t = threadIdx.x;
    const int w = t >> 6, l = t & 63;
    const int lr = l & 15, lg = l >> 4;
    const int row0 = blockIdx.y * 128, col0 = blockIdx.x * 128;
    const int wr = (w >> 1) * 64, wc = (w & 1) * 64;

    f32x4 acc[4][4];
#pragma unroll
    for (int i = 0; i < 4; ++i)
#pragma unroll
        for (int j = 0; j < 4; ++j) acc[i][j] = (f32x4){0.f, 0.f, 0.f, 0.f};

    const short* Ag = A + (size_t)(row0 + w * 32 + (l >> 2)) * K + (l & 3) * 8;
    const short* Bg = BT + (size_t)(col0 + w * 32 + (l >> 2)) * K + (l & 3) * 8;

    for (int k0 = 0; k0 < K; k0 += 32) {
        __syncthreads();
#pragma unroll
        for (int j = 0; j < 2; ++j) {
            GLD16(Ag + k0 + (size_t)j * 16 * K, As + (w * 2 + j) * 512);
            GLD16(Bg + k0 + (size_t)j * 16 * K, Bs + (w * 2 + j) * 512);
        }
        __syncthreads();

        bf16x8 af[4], bfr[4];
#pragma unroll
        for (int i = 0; i < 4; ++i)
            af[i] = *(const bf16x8*)(As + (wr + i * 16 + lr) * 32 + lg * 8);
#pragma unroll
        for (int j = 0; j < 4; ++j)
            bfr[j] = *(const bf16x8*)(Bs + (wc + j * 16 + lr) * 32 + lg * 8);
#pragma unroll
        for (int i = 0; i < 4; ++i)
#pragma unroll
            for (int j = 0; j < 4; ++j)
                acc[i][j] = __builtin_amdgcn_mfma_f32_16x16x32_bf16(af[i], bfr[j], acc[i][j], 0, 0, 0);
    }

#pragma unroll
    for (int i = 0; i < 4; ++i) {
#pragma unroll
        for (int j = 0; j < 4; ++j) {
            const int col = col0 + wc + j * 16 + lr;
            float bcol = (EPI >= 1) ? bias[col] : 0.f;
#pragma unroll
            for (int r = 0; r < 4; ++r) {
                const int row = row0 + wr + i * 16 + lg * 4 + r;
                float v = acc[i][j][r];
                if (EPI >= 1) v += bcol;
                if (EPI == 2) v = v / (1.0f + expf(-v));
                if (OUTBF) ((short*)Cout)[(size_t)row * N + col] = (short)f2bf(v);
                else       ((float*)Cout)[(size_t)row * N + col] = v;
            }
        }
    }
}

// ------------------------------------------------- RoPE + split + q2/k2 RMSNorm (bf16 io)
__global__ __launch_bounds__(256) void rope_kernel(const short* __restrict__ qkv,
                                                   const float* __restrict__ sigmas,
                                                   const float* __restrict__ lnq_w,
                                                   const float* __restrict__ lnq_b,
                                                   short* __restrict__ q1, short* __restrict__ q2n,
                                                   short* __restrict__ k1, short* __restrict__ k2n) {
    const int tok = blockIdx.x;            // 0..4095
    const int b = tok >> 11, s = tok & 2047;
    const int t = threadIdx.x;
    const int hh = t >> 4;                 // 0..15 (head in 2H layout)
    const int d0 = (t & 15) * 4;

    const short* qrow = qkv + (size_t)tok * 3072 + hh * 64 + d0;
    ushort4 qv = *(const ushort4*)qrow;
    ushort4 kv = *(const ushort4*)(qrow + 1024);
    float q[4] = {bf2f(qv.x), bf2f(qv.y), bf2f(qv.z), bf2f(qv.w)};
    float k[4] = {bf2f(kv.x), bf2f(kv.y), bf2f(kv.z), bf2f(kv.w)};

    if (d0 < 32) {
#pragma unroll
        for (int pr = 0; pr < 2; ++pr) {
            const int i = d0 / 2 + pr;
            float freq = (float)s * powf(10000.0f, -(float)i / 16.0f);
            float sn, c;
            sincosf(freq, &sn, &c);
            float x0 = q[2 * pr], x1 = q[2 * pr + 1];
            q[2 * pr]     = x0 * c - x1 * sn;
            q[2 * pr + 1] = x1 * c + x0 * sn;
            x0 = k[2 * pr]; x1 = k[2 * pr + 1];
            k[2 * pr]     = x0 * c - x1 * sn;
            k[2 * pr + 1] = x1 * c + x0 * sn;
        }
    }

    const int h = hh >> 1, j = hh & 1;
    const size_t obase = ((size_t)(b * H_ + h) * S_ + s) * 64 + d0;
    if (j == 0) {
        *(ushort4*)&q1[obase] = make_ushort4(f2bf(q[0]), f2bf(q[1]), f2bf(q[2]), f2bf(q[3]));
        *(ushort4*)&k1[obase] = make_ushort4(f2bf(k[0]), f2bf(k[1]), f2bf(k[2]), f2bf(k[3]));
    } else {
        float ssq_q = 0.f, ssq_k = 0.f;
#pragma unroll
        for (int i = 0; i < 4; ++i) {
            const float sg = sigmas[b * 64 + d0 + i];
            q[i] += sg; k[i] += sg;
            ssq_q += q[i] * q[i];
            ssq_k += k[i] * k[i];
        }
        for (int off = 1; off < 16; off <<= 1) {
            ssq_q += __shfl_xor(ssq_q, off, 16);
            ssq_k += __shfl_xor(ssq_k, off, 16);
        }
        const float rq = rsqrtf(ssq_q / 64.0f + 1e-8f);
        const float rk = rsqrtf(ssq_k / 64.0f + 1e-8f);
        float oq[4], ok[4];
#pragma unroll
        for (int i = 0; i < 4; ++i) {
            const float w = lnq_w[d0 + i], bb = lnq_b[d0 + i];
            oq[i] = q[i] * rq * w + bb;
            ok[i] = k[i] * rk * w + bb;
        }
        *(ushort4*)&q2n[obase] = make_ushort4(f2bf(oq[0]), f2bf(oq[1]), f2bf(oq[2]), f2bf(oq[3]));
        *(ushort4*)&k2n[obase] = make_ushort4(f2bf(ok[0]), f2bf(ok[1]), f2bf(ok[2]), f2bf(ok[3]));
    }
}

// ------------------------------------------------- softmax update (per wave, one branch)
__device__ __forceinline__ void sm_update(f32x4 (&s)[4], float (&m)[4], float (&lsum)[4],
                                          f32x4 (&o)[8], short* __restrict__ Pw,
                                          const bool diag, const int qr0, const int k0,
                                          const int lr, const int lg) {
    float nm[4];
#pragma unroll
    for (int r = 0; r < 4; ++r) nm[r] = m[r];
#pragma unroll
    for (int ks = 0; ks < 4; ++ks) {
#pragma unroll
        for (int r = 0; r < 4; ++r) {
            float v = s[ks][r];
            if (diag && (k0 + ks * 16 + lr > qr0 + r)) v = -INFINITY;
            else v *= 0.125f;
            s[ks][r] = v;
            nm[r] = fmaxf(nm[r], v);
        }
    }
#pragma unroll
    for (int r = 0; r < 4; ++r) {
        nm[r] = fmaxf(nm[r], __shfl_xor(nm[r], 1));
        nm[r] = fmaxf(nm[r], __shfl_xor(nm[r], 2));
        nm[r] = fmaxf(nm[r], __shfl_xor(nm[r], 4));
        nm[r] = fmaxf(nm[r], __shfl_xor(nm[r], 8));
    }
    float al[4], rs[4];
#pragma unroll
    for (int r = 0; r < 4; ++r) { al[r] = __expf(m[r] - nm[r]); m[r] = nm[r]; rs[r] = 0.f; }
#pragma unroll
    for (int ks = 0; ks < 4; ++ks) {
#pragma unroll
        for (int r = 0; r < 4; ++r) {
            float p = __expf(s[ks][r] - nm[r]);
            rs[r] += p;
            Pw[(lg * 4 + r) * 72 + ks * 16 + lr] = (short)f2bf(p);
        }
    }
#pragma unroll
    for (int r = 0; r < 4; ++r) {
        rs[r] += __shfl_xor(rs[r], 1);
        rs[r] += __shfl_xor(rs[r], 2);
        rs[r] += __shfl_xor(rs[r], 4);
        rs[r] += __shfl_xor(rs[r], 8);
        lsum[r] = lsum[r] * al[r] + rs[r];
    }
#pragma unroll
    for (int es = 0; es < 8; ++es) {
#pragma unroll
        for (int r = 0; r < 4; ++r) o[es][r] *= al[r];
    }
}

// ------------------------------------------------- dual attention, split-K partials
// 1D grid 512, XCD-swizzled (i&7 = XCD; each XCD owns 2 bh). Within an XCD the
// 64 blocks form a 2x32 table where BOTH adjacent-pair and stride-32-pair
// assignments give per-CU tile sums of exactly 17 (couples (16,1),(15,2)..(9,8);
// row a=1 is the elementwise complement of row a=0) -> uniform work per CU
// under either hardware block->CU pairing.
__global__ __launch_bounds__(512, 4) void attn_part(const short* __restrict__ q1g,
                                                    const short* __restrict__ q2g,
                                                    const short* __restrict__ k1g,
                                                    const short* __restrict__ k2g,
                                                    const short* __restrict__ vt,
                                                    short* __restrict__ pO0,
                                                    short* __restrict__ pO1,
                                                    float* __restrict__ pml) {
    __shared__ short Ks1[64 * 72];
    __shared__ short Ks2[64 * 72];
    __shared__ short Vt[128 * 72];
    __shared__ short Ps[8][16 * 72];   // per-wave P (reused across branches)

    const int i = blockIdx.x;            // 0..511
    const int xcd = i & 7;
    const int slot = i >> 3;             // 0..63
    const int a = slot >> 5, bb2 = slot & 31;
    const int k = bb2 >> 1, odd = bb2 & 1;
    const int k7 = k & 7;
    const int sz_even = 16 - k7, sz_odd = 1 + k7;
    const int sz = (a == 0) ? (odd ? sz_odd : sz_even) : (odd ? sz_even : sz_odd);
    const int qt = sz - 1;
    const int part = k >> 3;
    const int bh = xcd * 2 + a;
    const int q0 = qt * 128;
    const int t = threadIdx.x, w = t >> 6, l = t & 63;
    const int lr = l & 15, lg = l >> 4;

    const size_t kbase = (size_t)bh * S_ * 64;
    const size_t vbase = (size_t)bh * 128 * S_;

    // Q fragments (wave w owns rows q0 + w*16 .. +15)
    bf16x8 qa1[2], qa2[2];
    {
        const size_t rb = kbase + (size_t)(q0 + w * 16 + lr) * 64;
#pragma unroll
        for (int dh = 0; dh < 2; ++dh) {
            qa1[dh] = *(const bf16x8*)(q1g + rb + dh * 32 + lg * 8);
            qa2[dh] = *(const bf16x8*)(q2g + rb + dh * 32 + lg * 8);
        }
    }

    // part sizes are equal: nkt = 2(qt+1), mid = qt+1
    const int mid = qt + 1;
    const int kt0 = part ? mid : 0, kt1 = part ? 2 * mid : mid;

    float m1[4], m2[4], l1[4], l2[4];
#pragma unroll
    for (int r = 0; r < 4; ++r) { m1[r] = -1e30f; m2[r] = -1e30f; l1[r] = 0.f; l2[r] = 0.f; }
    f32x4 o1[8], o2[8];
#pragma unroll
    for (int es = 0; es < 8; ++es) { o1[es] = (f32x4){0.f,0.f,0.f,0.f}; o2[es] = (f32x4){0.f,0.f,0.f,0.f}; }

    short* Pw = &Ps[w][0];
    const int qr0 = q0 + w * 16 + lg * 4;
    const int wrow_lo = q0 + w * 16, wrow_hi = wrow_lo + 15;

    const int srow = t >> 3, scol = (t & 7) * 8;   // staging: 16B per thread per tile

    for (int kt = kt0; kt < kt1; ++kt) {
        const int k0 = kt * 64;
        __syncthreads();   // prior tile reads done
        // stage K1,K2 [64][72] and V^T [128][72] (vectorized 16B, coalesced)
        {
            const size_t g = kbase + (size_t)(k0 + srow) * 64 + scol;
            *(bf16x8*)(Ks1 + srow * 72 + scol) = *(const bf16x8*)(k1g + g);
            *(bf16x8*)(Ks2 + srow * 72 + scol) = *(const bf16x8*)(k2g + g);
            *(bf16x8*)(Vt + srow * 72 + scol) =
                *(const bf16x8*)(vt + vbase + (size_t)srow * S_ + k0 + scol);
            *(bf16x8*)(Vt + (srow + 64) * 72 + scol) =
                *(const bf16x8*)(vt + vbase + (size_t)(srow + 64) * S_ + k0 + scol);
        }
        __syncthreads();

        if (k0 > wrow_hi) continue;   // tile fully above this wave's diagonal
        const bool diag = (k0 + 63 > wrow_lo);

        // ---- branch 1
        {
            f32x4 s[4];
#pragma unroll
            for (int ks = 0; ks < 4; ++ks) s[ks] = (f32x4){0.f,0.f,0.f,0.f};
#pragma unroll
            for (int ks = 0; ks < 4; ++ks)
#pragma unroll
                for (int dh = 0; dh < 2; ++dh) {
                    bf16x8 kf = *(const bf16x8*)(Ks1 + (ks * 16 + lr) * 72 + dh * 32 + lg * 8);
                    s[ks] = __builtin_amdgcn_mfma_f32_16x16x32_bf16(qa1[dh], kf, s[ks], 0, 0, 0);
                }
            sm_update(s, m1, l1, o1, Pw, diag, qr0, k0, lr, lg);
#pragma unroll
            for (int kb = 0; kb < 2; ++kb) {
                bf16x8 pf = *(const bf16x8*)(Pw + lr * 72 + kb * 32 + lg * 8);
#pragma unroll
                for (int es = 0; es < 8; ++es) {
                    bf16x8 vf = *(const bf16x8*)(Vt + (es * 16 + lr) * 72 + kb * 32 + lg * 8);
                    o1[es] = __builtin_amdgcn_mfma_f32_16x16x32_bf16(pf, vf, o1[es], 0, 0, 0);
                }
            }
        }
        // ---- branch 2
        {
            f32x4 s[4];
#pragma unroll
            for (int ks = 0; ks < 4; ++ks) s[ks] = (f32x4){0.f,0.f,0.f,0.f};
#pragma unroll
            for (int ks = 0; ks < 4; ++ks)
#pragma unroll
                for (int dh = 0; dh < 2; ++dh) {
                    bf16x8 kf = *(const bf16x8*)(Ks2 + (ks * 16 + lr) * 72 + dh * 32 + lg * 8);
                    s[ks] = __builtin_amdgcn_mfma_f32_16x16x32_bf16(qa2[dh], kf, s[ks], 0, 0, 0);
                }
            sm_update(s, m2, l2, o2, Pw, diag, qr0, k0, lr, lg);
#pragma unroll
            for (int kb = 0; kb < 2; ++kb) {
                bf16x8 pf = *(const bf16x8*)(Pw + lr * 72 + kb * 32 + lg * 8);
#pragma unroll
                for (int es = 0; es < 8; ++es) {
                    bf16x8 vf = *(const bf16x8*)(Vt + (es * 16 + lr) * 72 + kb * 32 + lg * 8);
                    o2[es] = __builtin_amdgcn_mfma_f32_16x16x32_bf16(pf, vf, o2[es], 0, 0, 0);
                }
            }
        }
    }

    // store partials: packed 2xbf16 uints, wave-fragment layout, fully coalesced.
    // layout: pO[ wb + ((r*2 + br)*4 + u)*64 + lane ], wb = ((bh*16+qt)*8+w)*2048
    // where u packs (es=2u -> low16, es=2u+1 -> high16).
    {
        uint32_t* pO = (uint32_t*)(part ? pO1 : pO0);
        const size_t wb = (((size_t)bh * 16 + qt) * 8 + w) * 2048;
#pragma unroll
        for (int r = 0; r < 4; ++r) {
#pragma unroll
            for (int u = 0; u < 4; ++u) {
                uint32_t v1 = (uint32_t)f2bf(o1[2 * u][r]) | ((uint32_t)f2bf(o1[2 * u + 1][r]) << 16);
                pO[wb + (size_t)((r * 2 + 0) * 4 + u) * 64 + l] = v1;
                uint32_t v2 = (uint32_t)f2bf(o2[2 * u][r]) | ((uint32_t)f2bf(o2[2 * u + 1][r]) << 16);
                pO[wb + (size_t)((r * 2 + 1) * 4 + u) * 64 + l] = v2;
            }
        }
    }
    if (lr == 0) {
#pragma unroll
        for (int r = 0; r < 4; ++r) {
            const int q = q0 + w * 16 + lg * 4 + r;
            float4 v = make_float4(m1[r], l1[r], m2[r], l2[r]);
            *(float4*)&pml[(((size_t)part * 16 + bh) * S_ + q) * 4] = v;
        }
    }
}

// ------------------------------------------------- combine partials + diff + RMSNorm
__global__ __launch_bounds__(256) void attn_combine(const short* __restrict__ pO0,
                                                    const short* __restrict__ pO1,
                                                    const float* __restrict__ pml,
                                                    const float* __restrict__ lamp,
                                                    const float* __restrict__ ln_w,
                                                    const float* __restrict__ ln_b,
                                                    short* __restrict__ arms) {
    const int tok = blockIdx.x;           // 0..4095
    const int b = tok >> 11, q = tok & 2047;
    const int t = threadIdx.x;
    const int h = t >> 5, ln32 = t & 31, e0 = ln32 * 4;
    const int bh = b * H_ + h;
    const float lam = lamp[0];

    float4 mla = *(const float4*)&pml[(((size_t)0 * 16 + bh) * S_ + q) * 4];
    float4 mlb = *(const float4*)&pml[(((size_t)1 * 16 + bh) * S_ + q) * 4];

    const float m1 = fmaxf(mla.x, mlb.x);
    const float aa1 = __expf(mla.x - m1), ab1 = __expf(mlb.x - m1);
    const float il1 = 1.0f / (aa1 * mla.y + ab1 * mlb.y);
    const float m2 = fmaxf(mla.z, mlb.z);
    const float aa2 = __expf(mla.z - m2), ab2 = __expf(mlb.z - m2);
    const float il2 = 1.0f / (aa2 * mla.w + ab2 * mlb.w);

    // decode packed wave-fragment layout
    const int qt = q >> 7, w = (q >> 4) & 7, lg = (q >> 2) & 3, r = q & 3;
    const int es = ln32 >> 2, u = es >> 1, half = es & 1;
    const int lane0 = lg * 16 + (ln32 & 3) * 4;
    const size_t wb = (((size_t)bh * 16 + qt) * 8 + w) * 2048;
    const uint32_t* P0 = (const uint32_t*)pO0;
    const uint32_t* P1 = (const uint32_t*)pO1;
    const uint4 a1  = *(const uint4*)&P0[wb + (size_t)((r * 2 + 0) * 4 + u) * 64 + lane0];
    const uint4 b1v = *(const uint4*)&P1[wb + (size_t)((r * 2 + 0) * 4 + u) * 64 + lane0];
    const uint4 a2  = *(const uint4*)&P0[wb + (size_t)((r * 2 + 1) * 4 + u) * 64 + lane0];
    const uint4 b2v = *(const uint4*)&P1[wb + (size_t)((r * 2 + 1) * 4 + u) * 64 + lane0];
    const int sh = 16 * half;

    float comb[4]; float ssq = 0.f;
    {
        const uint32_t aw1[4] = {a1.x, a1.y, a1.z, a1.w};
        const uint32_t bw1[4] = {b1v.x, b1v.y, b1v.z, b1v.w};
        const uint32_t aw2[4] = {a2.x, a2.y, a2.z, a2.w};
        const uint32_t bw2[4] = {b2v.x, b2v.y, b2v.z, b2v.w};
#pragma unroll
        for (int i = 0; i < 4; ++i) {
            const float O1 = (aa1 * bf2f((unsigned short)(aw1[i] >> sh)) +
                              ab1 * bf2f((unsigned short)(bw1[i] >> sh))) * il1;
            const float O2 = (aa2 * bf2f((unsigned short)(aw2[i] >> sh)) +
                              ab2 * bf2f((unsigned short)(bw2[i] >> sh))) * il2;
            const float c = O1 - lam * O2;
            comb[i] = c; ssq += c * c;
        }
    }
    for (int off = 1; off < 32; off <<= 1) ssq += __shfl_xor(ssq, off, 32);
    const float rms = rsqrtf(ssq / 128.0f + 1e-8f);

    ushort4 o;
    unsigned short* op = (unsigned short*)&o;
#pragma unroll
    for (int i = 0; i < 4; ++i) {
        const int e = e0 + i;
        op[i] = f2bf((comb[i] * rms * ln_w[e] + ln_b[e]) * ONE_MINUS_LI);
    }
    *(ushort4*)&arms[(size_t)tok * 1024 + h * 128 + e0] = o;
}

// ---------------------------------------------------------------- add + LayerNorm
template <int WB>
__global__ __launch_bounds__(256) void add_ln_kernel(const float* __restrict__ X,
                                                     const float* __restrict__ Y,
                                                     const float* __restrict__ w,
                                                     const float* __restrict__ bvec,
                                                     float* __restrict__ out,
                                                     short* __restrict__ out_bf,
                                                     float eps) {
    const int row = blockIdx.x;
    const int t = threadIdx.x;
    __shared__ float red[4];

    float4 xv = *(const float4*)&X[(size_t)row * 1024 + t * 4];
    float4 yv = *(const float4*)&Y[(size_t)row * 1024 + t * 4];
    float v[4] = {xv.x + yv.x, xv.y + yv.y, xv.z + yv.z, xv.w + yv.w};

    float s = v[0] + v[1] + v[2] + v[3];
    for (int off = 1; off < 64; off <<= 1) s += __shfl_xor(s, off);
    if ((t & 63) == 0) red[t >> 6] = s;
    __syncthreads();
    const float mean = (red[0] + red[1] + red[2] + red[3]) * (1.0f / 1024.0f);

    float sq = 0.f;
#pragma unroll
    for (int i = 0; i < 4; ++i) { const float d = v[i] - mean; sq += d * d; }
    __syncthreads();
    for (int off = 1; off < 64; off <<= 1) sq += __shfl_xor(sq, off);
    if ((t & 63) == 0) red[t >> 6] = sq;
    __syncthreads();
    const float var = (red[0] + red[1] + red[2] + red[3]) * (1.0f / 1024.0f);
    const float rstd = rsqrtf(var + eps);

    float o[4];
#pragma unroll
    for (int i = 0; i < 4; ++i)
        o[i] = (v[i] - mean) * rstd * w[t * 4 + i] + bvec[t * 4 + i];
    *(float4*)&out[(size_t)row * 1024 + t * 4] = make_float4(o[0], o[1], o[2], o[3]);
    if (WB) {
        *(ushort4*)&out_bf[(size_t)row * 1024 + t * 4] =
            make_ushort4(f2bf(o[0]), f2bf(o[1]), f2bf(o[2]), f2bf(o[3]));
    }
}

// ---------------------------------------------------------------- launch
extern "C" void kernel_launch(void* const* d_in, const int* in_sizes, int n_in,
                              void* d_out, int out_size, void* d_ws, size_t ws_size,
                              hipStream_t stream) {
    const float* x      = (const float*)d_in[0];
    const float* sigmas = (const float*)d_in[1];
    const float* w_qkv  = (const float*)d_in[2];
    const float* w_out  = (const float*)d_in[3];
    const float* lq1    = (const float*)d_in[4];
    const float* lk1    = (const float*)d_in[5];
    const float* lq2    = (const float*)d_in[6];
    const float* lk2    = (const float*)d_in[7];
    const float* ln_w   = (const float*)d_in[8];
    const float* ln_b   = (const float*)d_in[9];
    const float* lnq_w  = (const float*)d_in[10];
    const float* lnq_b  = (const float*)d_in[11];
    const float* ln1_w  = (const float*)d_in[12];
    const float* ln1_b  = (const float*)d_in[13];
    const float* ln2_w  = (const float*)d_in[14];
    const float* ln2_b  = (const float*)d_in[15];
    const float* w1     = (const float*)d_in[16];
    const float* b1     = (const float*)d_in[17];
    const float* w2     = (const float*)d_in[18];
    const float* b2     = (const float*)d_in[19];

    char* ws = (char*)d_ws;
    short* x_bf    = (short*)(ws + 0);            //  8,388,608 (-> vt after qkv gemm)
    short* vt      = (short*)(ws + 0);            //  8,388,608 exactly
    short* w_qkvT  = (short*)(ws + 8388608);      //  6,291,456
    short* w_outT  = (short*)(ws + 14680064);     //  2,097,152
    short* w1T     = (short*)(ws + 16777216);     //  8,388,608
    short* w2T     = (short*)(ws + 25165824);     //  8,388,608
    short* qkv_bf  = (short*)(ws + 33554432);     // 25,165,824 (dead after rope+vtrans)
    short* pO0     = (short*)(ws + 33554432);     // 16,777,216
    float* pml     = (float*)(ws + 50331648);     //  1,048,576
    short* q1      = (short*)(ws + 58720256);     //  4,194,304
    short* q2n     = (short*)(ws + 62914560);
    short* k1      = (short*)(ws + 67108864);
    short* k2n     = (short*)(ws + 71303168);     // ends 75,497,472
    short* arms    = (short*)(ws + 75497472);     //  8,388,608
    short* pO1     = (short*)(ws + 83886080);     // 16,777,216 (-> a_f32 after combine)
    float* a_f32   = (float*)(ws + 83886080);
    float* h_f32   = (float*)(ws + 33554432);     // reuse pO0+pml region after combine
    short* h_bf    = (short*)(ws + 50331648);     //  8,388,608
    short* ffh     = (short*)(ws + 58720256);     // 33,554,432 (q/k + arms dead)
    float* ff      = (float*)(ws + 0);            // 16,777,216 (vt + w_qkvT dead)
    float* lam     = (float*)(ws + 100663296);

    // 1. lambda
    lam_kernel<<<1, 64, 0, stream>>>(lq1, lk1, lq2, lk2, lam);

    // 2. conversions
    convert_bf16<<<4096, 256, 0, stream>>>(x, x_bf);
    transpose_to_bf16<<<dim3(3072 / 32, 1024 / 32), 256, 0, stream>>>(w_qkv, w_qkvT, 1024, 3072);
    transpose_to_bf16<<<dim3(1024 / 32, 1024 / 32), 256, 0, stream>>>(w_out, w_outT, 1024, 1024);
    transpose_to_bf16<<<dim3(4096 / 32, 1024 / 32), 256, 0, stream>>>(w1, w1T, 1024, 4096);
    transpose_to_bf16<<<dim3(1024 / 32, 4096 / 32), 256, 0, stream>>>(w2, w2T, 4096, 1024);

    // 3. qkv = x @ w_qkv  -> bf16
    gemm_bt<0, 1><<<dim3(3072 / 128, 4096 / 128), 256, 0, stream>>>(x_bf, w_qkvT, nullptr,
                                                                    qkv_bf, NT_, 3072, 1024);

    // 4. rope + split + q2/k2 rmsnorm ; V transpose (x_bf dead now)
    rope_kernel<<<NT_, 256, 0, stream>>>(qkv_bf, sigmas, lnq_w, lnq_b, q1, q2n, k1, k2n);
    vtrans_kernel<<<dim3(S_ / 32, 4, 16), 256, 0, stream>>>(qkv_bf, vt);

    // 5. dual attention split-K partials (balanced XCD-swizzled grid) + combine
    attn_part<<<512, 512, 0, stream>>>(q1, q2n, k1, k2n, vt, pO0, pO1, pml);
    attn_combine<<<NT_, 256, 0, stream>>>(pO0, pO1, pml, lam, ln_w, ln_b, arms);

    // 6. a = arms @ w_out -> f32
    gemm_bt<0, 0><<<dim3(1024 / 128, 4096 / 128), 256, 0, stream>>>(arms, w_outT, nullptr,
                                                                    a_f32, NT_, 1024, 1024);

    // 7. h = LN(a + x) -> f32 + bf16
    add_ln_kernel<1><<<NT_, 256, 0, stream>>>(a_f32, x, ln1_w, ln1_b, h_f32, h_bf, 1e-5f);

    // 8. ffh = silu(h @ w1 + b1) -> bf16
    gemm_bt<2, 1><<<dim3(4096 / 128, 4096 / 128), 256, 0, stream>>>(h_bf, w1T, b1,
                                                                    ffh, NT_, 4096, 1024);

    // 9. ff = ffh @ w2 + b2 -> f32
    gemm_bt<1, 0><<<dim3(1024 / 128, 4096 / 128), 256, 0, stream>>>(ffh, w2T, b2,
                                                                    ff, NT_, 1024, 4096);

    // 10. out = LN(ff + h)
    add_ln_kernel<0><<<NT_, 256, 0, stream>>>(ff, h_f32, ln2_w, ln2_b, (float*)d_out,
                                              nullptr, 1e-5f);
}